// Round 1
// baseline (225.969 us; speedup 1.0000x reference)
//
#include <hip/hip_runtime.h>
#include <math.h>

// EfficientDet post-processing v12 (6 launches).
// prep(transpose vec4) -> select(sorted top-512 per (class,slice) + decode)
// -> sort(resume-bitonic 2048 -> sorted top-512 SoA)
// -> mask(wave-per-row IoU, ballot bit-pack, 360 blocks)
// -> scan(greedy NMS scan + compact)
// -> final(hist-select top-100 over <=9000 kept entries).

#define A_N   110484
#define C_N   90
#define KCAND 512
#define NBINS 8192        // 13-bit histogram bins (key >> 19)
#define KSH   19
#define MAXDET 100
#define IMG_F 768.0f
#define THRESH 0.05f
#define NS    4                                   // slices per class
#define VTOT  (A_N / 4)                           // 27621 vec4 units
#define VS4   ((VTOT + NS - 1) / NS)              // 6906
#define SL_CAP 1024                               // per-slice candidate cap
#define CAND_N (NS * KCAND)                       // 2048 per class (sorted runs)
#define KEEP_CAP 100
#define T_BLKS ((A_N + 63) / 64)                  // 1727 transpose blocks
#define S_BLKS (C_N * NS)                         // 360 select blocks
#define D_BLKS ((A_N + 255) / 256)                // 432 decode blocks
#define FCAP  512                                 // final collect capacity
#define STRIPS 4                                  // mask blocks per class

typedef unsigned int u32;
typedef unsigned long long u64;

__device__ __forceinline__ u32 fkey(float f) {
    u32 u = __float_as_uint(f);
    return (u & 0x80000000u) ? ~u : (u | 0x80000000u);
}
__device__ __forceinline__ float unfkey(u32 k) {
    u32 u = (k & 0x80000000u) ? (k ^ 0x80000000u) : ~k;
    return __uint_as_float(u);
}
__device__ __forceinline__ u64 shflx64(u64 v, int m) {
    u32 lo = (u32)__shfl_xor((int)(u32)v, m, 64);
    u32 hi = (u32)__shfl_xor((int)(v >> 32), m, 64);
    return ((u64)hi << 32) | lo;
}

// ------- Stage 1: transpose (sigmoid->key, vec4 loads) -------
__global__ __launch_bounds__(256)
void prep_kernel(const float* __restrict__ cls,
                 u32* __restrict__ keysT) {
    __shared__ u32 tile[64 * 91];   // 23.3 KB, stride 91 (odd) = conflict-free
    const int a0 = blockIdx.x * 64;
    const int lim = min(64, A_N - a0);           // 64 or 20; lim*90 % 4 == 0
    const int n4 = (lim * C_N) >> 2;
    const float4* src4 = (const float4*)(cls + (size_t)a0 * C_N);
    for (int i4 = threadIdx.x; i4 < n4; i4 += 256) {
        float4 x4 = src4[i4];
        const u32 base = (u32)(4 * i4);
        float xs[4] = { x4.x, x4.y, x4.z, x4.w };
        #pragma unroll
        for (int k = 0; k < 4; ++k) {
            u32 i = base + k;
            u32 aa = i / C_N, c = i % C_N;
            float s = 1.0f / (1.0f + expf(-xs[k]));
            tile[aa * 91 + c] = fkey(s);
        }
    }
    __syncthreads();
    for (int j = threadIdx.x; j < C_N * 64; j += 256) {
        int c = j >> 6, aa = j & 63;
        if (aa < lim)
            keysT[(size_t)c * A_N + a0 + aa] = tile[aa * 91 + c];
    }
}

// ---- Stage 2: per-(class,slice) exact sorted top-512 (+ decode blocks) ----
__global__ __launch_bounds__(256)
void select_kernel(const u32* __restrict__ keysT,
                   const float* __restrict__ anchors,
                   const float* __restrict__ reg,
                   float4* __restrict__ boxes,
                   u64* __restrict__ candbuf) {
    __shared__ u32 hist[NBINS];    // 32 KB
    __shared__ u32 csum[256];
    __shared__ u64 lbuf[SL_CAP];   // 8 KB
    __shared__ u32 sPv;
    __shared__ int lcnt;
    const int tid = threadIdx.x;

    if (blockIdx.x >= S_BLKS) {    // decode blocks
        int a = (blockIdx.x - S_BLKS) * 256 + tid;
        if (a < A_N) {
            float4 an = ((const float4*)anchors)[a];
            float4 dl = ((const float4*)reg)[a];
            float wa = an.z - an.x, ha = an.w - an.y;
            float cx = an.x + 0.5f * wa + dl.x * wa;
            float cy = an.y + 0.5f * ha + dl.y * ha;
            float w = expf(dl.z) * wa;
            float h = expf(dl.w) * ha;
            float4 o;
            o.x = fminf(fmaxf(cx - 0.5f * w, 0.0f), IMG_F);
            o.y = fminf(fmaxf(cy - 0.5f * h, 0.0f), IMG_F);
            o.z = fminf(fmaxf(cx + 0.5f * w, 0.0f), IMG_F);
            o.w = fminf(fmaxf(cy + 0.5f * h, 0.0f), IMG_F);
            boxes[a] = o;
        }
        return;
    }
    const int c = blockIdx.x >> 2, s = blockIdx.x & 3;
    const int lo = s * VS4, hiEnd = min(VTOT, lo + VS4);
    const uint4* kv = (const uint4*)(keysT + (size_t)c * A_N);

    for (int i = tid; i < NBINS; i += 256) hist[i] = 0;
    if (tid == 0) { sPv = 0; lcnt = 0; }
    __syncthreads();
    for (int i = lo + tid; i < hiEnd; i += 256) {
        uint4 k = kv[i];
        atomicAdd(&hist[k.x >> KSH], 1u);
        atomicAdd(&hist[k.y >> KSH], 1u);
        atomicAdd(&hist[k.z >> KSH], 1u);
        atomicAdd(&hist[k.w >> KSH], 1u);
    }
    __syncthreads();
    u32 own = 0; const int hi = NBINS - 1 - 32 * tid;
    #pragma unroll 4
    for (int j = 0; j < 32; ++j) own += hist[hi - j];
    csum[tid] = own;
    __syncthreads();
    for (int off = 1; off < 256; off <<= 1) {
        u32 v = csum[tid];
        u32 a = (tid >= off) ? csum[tid - off] : 0u;
        __syncthreads();
        csum[tid] = v + a;
        __syncthreads();
    }
    const u32 incl = csum[tid], excl = incl - own;
    if (excl < (u32)KCAND && incl >= (u32)KCAND) {
        u32 cum = excl;
        for (int j = 0; j < 32; ++j) {
            u32 hv = hist[hi - j];
            if (cum + hv >= (u32)KCAND) { sPv = (u32)(hi - j); break; }
            cum += hv;
        }
    }
    __syncthreads();
    const u32 P = sPv;
    for (int i = lo + tid; i < hiEnd; i += 256) {
        uint4 k = kv[i];
        u32 base = (u32)(4 * i);
        if ((k.x >> KSH) >= P) {
            int p = atomicAdd(&lcnt, 1);
            if (p < SL_CAP) lbuf[p] = (((u64)(~k.x)) << 32) | base;
        }
        if ((k.y >> KSH) >= P) {
            int p = atomicAdd(&lcnt, 1);
            if (p < SL_CAP) lbuf[p] = (((u64)(~k.y)) << 32) | (base + 1);
        }
        if ((k.z >> KSH) >= P) {
            int p = atomicAdd(&lcnt, 1);
            if (p < SL_CAP) lbuf[p] = (((u64)(~k.z)) << 32) | (base + 2);
        }
        if ((k.w >> KSH) >= P) {
            int p = atomicAdd(&lcnt, 1);
            if (p < SL_CAP) lbuf[p] = (((u64)(~k.w)) << 32) | (base + 3);
        }
    }
    __syncthreads();
    const int n = min(lcnt, SL_CAP);   // n >= 512 guaranteed by pivot
    for (int i = tid; i < SL_CAP; i += 256) if (i >= n) lbuf[i] = ~0ULL;
    __syncthreads();

    // --- hybrid bitonic 1024 sort: 4 waves x (4 regs x 64 lanes) ---
    {
        const int l = tid & 63, w = tid >> 6;
        int ii[4]; u64 v[4];
        #pragma unroll
        for (int r = 0; r < 4; ++r) { ii[r] = 256 * w + 64 * r + l; v[r] = lbuf[ii[r]]; }
        __syncthreads();
        #pragma unroll
        for (u32 kk = 2; kk <= 1024; kk <<= 1) {
            #pragma unroll
            for (u32 j = kk >> 1; j > 0; j >>= 1) {
                if (j >= 256) {
                    #pragma unroll
                    for (int r = 0; r < 4; ++r) lbuf[ii[r]] = v[r];
                    __syncthreads();
                    #pragma unroll
                    for (int r = 0; r < 4; ++r) {
                        u64 pv = lbuf[ii[r] ^ j];
                        bool up = ((ii[r] & kk) == 0);
                        bool m = (((ii[r] & j) == 0) == up);
                        v[r] = m ? (v[r] < pv ? v[r] : pv) : (v[r] > pv ? v[r] : pv);
                    }
                    __syncthreads();
                } else if (j >= 64) {
                    const int rx = (int)(j >> 6);   // 1 or 2
                    u64 nv[4];
                    #pragma unroll
                    for (int r = 0; r < 4; ++r) {
                        u64 pv = v[r ^ rx];
                        bool up = ((ii[r] & kk) == 0);
                        bool m = (((ii[r] & j) == 0) == up);
                        nv[r] = m ? (v[r] < pv ? v[r] : pv) : (v[r] > pv ? v[r] : pv);
                    }
                    #pragma unroll
                    for (int r = 0; r < 4; ++r) v[r] = nv[r];
                } else {
                    #pragma unroll
                    for (int r = 0; r < 4; ++r) {
                        u64 pv = shflx64(v[r], (int)j);
                        bool up = ((ii[r] & kk) == 0);
                        bool m = (((ii[r] & j) == 0) == up);
                        v[r] = m ? (v[r] < pv ? v[r] : pv) : (v[r] > pv ? v[r] : pv);
                    }
                }
            }
        }
        u64* cb = candbuf + (size_t)c * CAND_N + (size_t)s * KCAND;
        const bool rev = (s & 1);
        #pragma unroll
        for (int r = 0; r < 4; ++r) {
            if (ii[r] < KCAND) {
                int d = rev ? (KCAND - 1 - ii[r]) : ii[r];
                cb[d] = v[r];
            }
        }
    }
}

// ---- Stage 3a: resume-bitonic(2048) -> sorted top-512 scores/boxes ----
__global__ __launch_bounds__(1024)
void sort_kernel(const u64* __restrict__ candbuf,
                 const float4* __restrict__ boxes,
                 float4* __restrict__ sbox, float* __restrict__ ssc) {
    __shared__ u64 sortbuf[2][CAND_N];     // 32 KB
    const int c = blockIdx.x, tid = threadIdx.x;
    const int l = tid & 63, w = tid >> 6;
    const int i0 = 128 * w + l, i1 = i0 + 64;

    // input: 4 sorted runs of 512, alternating asc/desc = post-stage-512 state
    const u64* cb = candbuf + (size_t)c * CAND_N;
    u64 v0 = cb[i0], v1 = cb[i1];
    int p = 0;
    #pragma unroll
    for (u32 kk = 1024; kk <= (u32)CAND_N; kk <<= 1) {
        #pragma unroll
        for (u32 j = kk >> 1; j > 0; j >>= 1) {
            if (j >= 128) {
                sortbuf[p][i0] = v0; sortbuf[p][i1] = v1;
                __syncthreads();
                u64 w0 = sortbuf[p][i0 ^ j], w1 = sortbuf[p][i1 ^ j];
                bool m0 = (((i0 & j) == 0) == ((i0 & kk) == 0));
                bool m1 = (((i1 & j) == 0) == ((i1 & kk) == 0));
                v0 = m0 ? (v0 < w0 ? v0 : w0) : (v0 > w0 ? v0 : w0);
                v1 = m1 ? (v1 < w1 ? v1 : w1) : (v1 > w1 ? v1 : w1);
                p ^= 1;
            } else if (j == 64) {
                bool up = ((i0 & kk) == 0);
                u64 mn = v0 < v1 ? v0 : v1, mx = v0 < v1 ? v1 : v0;
                v0 = up ? mn : mx; v1 = up ? mx : mn;
            } else {
                u64 w0 = shflx64(v0, (int)j), w1 = shflx64(v1, (int)j);
                bool m0 = (((i0 & j) == 0) == ((i0 & kk) == 0));
                bool m1 = (((i1 & j) == 0) == ((i1 & kk) == 0));
                v0 = m0 ? (v0 < w0 ? v0 : w0) : (v0 > w0 ? v0 : w0);
                v1 = m1 ? (v1 < w1 ? v1 : w1) : (v1 > w1 ? v1 : w1);
            }
        }
    }
    // top-512 (ranks i0,i1 < 512 live in waves w<4) -> global SoA
    if (w < 4) {
        u32 idx0 = (u32)v0, key0 = ~((u32)(v0 >> 32));
        u32 idx1 = (u32)v1, key1 = ~((u32)(v1 >> 32));
        ssc[(size_t)c * KCAND + i0] = unfkey(key0);
        ssc[(size_t)c * KCAND + i1] = unfkey(key1);
        sbox[(size_t)c * KCAND + i0] = boxes[idx0];
        sbox[(size_t)c * KCAND + i1] = boxes[idx1];
    }
}

// ---- Stage 3b: IoU mask, wave-per-row, ballot bit-pack, 4 blocks/class ----
__global__ __launch_bounds__(256)
void mask_kernel(const float4* __restrict__ sbox, u32* __restrict__ gmask) {
    __shared__ float4 bb[KCAND];   // 8 KB
    const int c = blockIdx.x >> 2, s = blockIdx.x & 3;
    const int tid = threadIdx.x;
    const int l = tid & 63, wv = tid >> 6;
    const float4* sb = sbox + (size_t)c * KCAND;
    for (int i = tid; i < KCAND; i += 256) bb[i] = sb[i];
    __syncthreads();
    const int wid = 4 * s + wv;     // 0..15, rows round-robin for balance
    u32* gm = gmask + (size_t)c * KCAND * 16;
    for (int r = wid; r < KCAND; r += 16) {
        const float4 bi = bb[r];                          // broadcast read
        const float ai = (bi.z - bi.x) * (bi.w - bi.y);
        const int q0 = (r + 1) >> 6;
        u32* row = gm + r * 16;
        if (l < 2 * q0) row[l] = 0;                       // words below diagonal
        for (int q = q0; q < 8; ++q) {                    // wave-uniform bounds
            const int j = q * 64 + l;                     // consecutive lanes ->
            const float4 bj = bb[j];                      // conflict-free b128
            float xx1 = fmaxf(bi.x, bj.x), yy1 = fmaxf(bi.y, bj.y);
            float xx2 = fminf(bi.z, bj.z), yy2 = fminf(bi.w, bj.w);
            float inter = fmaxf(xx2 - xx1, 0.0f) * fmaxf(yy2 - yy1, 0.0f);
            float aj = (bj.z - bj.x) * (bj.w - bj.y);
            float uni = ai + aj - inter + 1e-8f;          // identical expr order
            bool sup = (j > r) && (inter > 0.5f * uni);
            u64 bal = __ballot(sup);
            if (l == 0)      row[2 * q]     = (u32)bal;
            else if (l == 1) row[2 * q + 1] = (u32)(bal >> 32);
        }
    }
}

// ---- Stage 3c: greedy scan + compact ----
__global__ __launch_bounds__(512)
void scan_kernel(const u32* __restrict__ gmask,
                 const float4* __restrict__ sbox,
                 const float* __restrict__ ssc,
                 u32* __restrict__ keptbuf, u32* __restrict__ cnt2) {
    __shared__ u32 bmask[KCAND * 16];  // 32 KB
    __shared__ float sc[KCAND];
    __shared__ float4 bb[KCAND];       // 8 KB
    __shared__ u32 keepf[16], wbase[17];
    const int c = blockIdx.x, tid = threadIdx.x;

    const uint4* gm4 = (const uint4*)(gmask + (size_t)c * KCAND * 16);
    uint4* bm4 = (uint4*)bmask;
    #pragma unroll
    for (int i = 0; i < 4; ++i) bm4[tid + 512 * i] = gm4[tid + 512 * i];
    sc[tid] = ssc[(size_t)c * KCAND + tid];
    bb[tid] = sbox[(size_t)c * KCAND + tid];
    if (tid < 16) keepf[tid] = 0;
    __syncthreads();

    // --- greedy scan, wave 0; register-pipelined rows + readlane chain ---
    if (tid < 64) {
        const int lw = tid & 15;
        u32 removed = 0, keepw = 0;
        u32 rA[8], rB[8]; float sA[8], sB[8];
        #pragma unroll
        for (int k = 0; k < 8; ++k) { rA[k] = bmask[k * 16 + lw]; sA[k] = sc[k]; }
        #pragma unroll 1
        for (int ch = 0; ch < 64; ch += 2) {
            const int tb1 = (ch + 1) * 8;
            #pragma unroll
            for (int k = 0; k < 8; ++k) { rB[k] = bmask[(tb1 + k) * 16 + lw]; sB[k] = sc[tb1 + k]; }
            {
                const int tb = ch * 8;
                #pragma unroll
                for (int k = 0; k < 8; ++k) {
                    const int t = tb + k;
                    u32 rw = (u32)__builtin_amdgcn_readlane((int)removed, t >> 5);
                    bool d = (sA[k] > THRESH) && (((rw >> (t & 31)) & 1u) == 0u);
                    removed |= d ? rA[k] : 0u;
                    keepw |= (d && (tid == (t >> 5))) ? (1u << (t & 31)) : 0u;
                }
            }
            const int tb2 = (ch + 2 < 64) ? (ch + 2) * 8 : 0;
            #pragma unroll
            for (int k = 0; k < 8; ++k) { rA[k] = bmask[(tb2 + k) * 16 + lw]; sA[k] = sc[tb2 + k]; }
            {
                #pragma unroll
                for (int k = 0; k < 8; ++k) {
                    const int t = tb1 + k;
                    u32 rw = (u32)__builtin_amdgcn_readlane((int)removed, t >> 5);
                    bool d = (sB[k] > THRESH) && (((rw >> (t & 31)) & 1u) == 0u);
                    removed |= d ? rB[k] : 0u;
                    keepw |= (d && (tid == (t >> 5))) ? (1u << (t & 31)) : 0u;
                }
            }
        }
        if (tid < 16) keepf[tid] = keepw;
    }
    __syncthreads();

    // --- compact kept (sorted order) to keptbuf, cap 100/class ---
    if (tid == 0) {
        u32 t = 0;
        for (int q = 0; q < 16; ++q) { wbase[q] = t; t += __popc(keepf[q]); }
        wbase[16] = t;
        cnt2[c] = (t < (u32)KEEP_CAP) ? t : (u32)KEEP_CAP;
    }
    __syncthreads();
    {
        u32 word = keepf[tid >> 5];
        u32 bit = (u32)tid & 31u;
        if ((word >> bit) & 1u) {
            u32 rank = wbase[tid >> 5] + __popc(word & ((1u << bit) - 1u));
            if (rank < (u32)KEEP_CAP) {
                float s = sc[tid];
                float4 b = bb[tid];
                uint4 a2, b2;
                a2.x = ~fkey(s);
                a2.y = (u32)(c * KCAND + tid);
                a2.z = __float_as_uint(b.x);
                a2.w = __float_as_uint(b.y);
                b2.x = __float_as_uint(b.z);
                b2.y = __float_as_uint(b.w);
                b2.z = __float_as_uint(s);
                b2.w = 0u;
                uint4* e = (uint4*)(keptbuf + ((size_t)c * KEEP_CAP + rank) * 8);
                e[0] = a2; e[1] = b2;
            }
        }
    }
}

// ---- Stage 4: global top-100 via hist-select over <=9000 kept entries ----
__global__ __launch_bounds__(1024)
void final_kernel(const u32* __restrict__ keptbuf, const u32* __restrict__ cnt2,
                  float* __restrict__ out) {
    __shared__ u32 hist[NBINS];    // 32 KB
    __shared__ u32 csum[1024];     // 4 KB
    __shared__ u64 ebuf[FCAP];     // 4 KB keys
    __shared__ u32 eidx[FCAP];     // 2 KB payload (keptbuf entry index)
    __shared__ u32 scnt[C_N];
    __shared__ u32 sP;
    __shared__ int sN;
    const int tid = threadIdx.x;
    const int TOT = C_N * KEEP_CAP;   // 9000

    for (int i = tid; i < MAXDET * 7; i += 1024) out[i] = 0.0f;
    for (int i = tid; i < NBINS; i += 1024) hist[i] = 0;
    if (tid < C_N) scnt[tid] = cnt2[tid];
    if (tid == 0) { sN = 0; sP = NBINS - 1; }
    __syncthreads();

    // hist over composite high word (smaller = better -> ascending pivot)
    for (int i = tid; i < TOT; i += 1024) {
        u32 c = (u32)i / KEEP_CAP, pp = (u32)i % KEEP_CAP;
        if (pp < scnt[c]) {
            u32 khi = keptbuf[(size_t)i * 8];   // a.x = ~fkey(s)
            atomicAdd(&hist[khi >> KSH], 1u);
        }
    }
    __syncthreads();
    // ascending chunk sums (8 bins each) + Hillis-Steele scan
    u32 own = 0; const int lo = 8 * tid;
    #pragma unroll
    for (int j = 0; j < 8; ++j) own += hist[lo + j];
    csum[tid] = own;
    __syncthreads();
    for (int off = 1; off < 1024; off <<= 1) {
        u32 v = csum[tid];
        u32 a = (tid >= off) ? csum[tid - off] : 0u;
        __syncthreads();
        csum[tid] = v + a;
        __syncthreads();
    }
    const u32 incl = csum[tid], excl = incl - own;
    if (excl < (u32)MAXDET && incl >= (u32)MAXDET) {
        u32 cum = excl;
        for (int j = 0; j < 8; ++j) {
            u32 h = hist[lo + j];
            if (cum + h >= (u32)MAXDET) { sP = (u32)(lo + j); break; }
            cum += h;
        }
    }
    __syncthreads();
    const u32 P = sP;
    // collect entries with bin <= P
    for (int i = tid; i < TOT; i += 1024) {
        u32 c = (u32)i / KEEP_CAP, pp = (u32)i % KEEP_CAP;
        if (pp < scnt[c]) {
            const uint2 v2 = *((const uint2*)(keptbuf + (size_t)i * 8));
            if ((v2.x >> KSH) <= P) {
                int p = atomicAdd(&sN, 1);
                if (p < FCAP) {
                    ebuf[p] = ((u64)v2.x << 32) | v2.y;
                    eidx[p] = (u32)i;
                }
            }
        }
    }
    __syncthreads();
    const int n = min(sN, FCAP);
    u32 m = 128; while ((int)m < n) m <<= 1;   // 128..512, uniform
    for (int i = tid; i < (int)m; i += 1024) if (i >= n) ebuf[i] = ~0ULL;
    __syncthreads();
    // bitonic sort (key ebuf asc, payload eidx follows)
    for (u32 kk = 2; kk <= m; kk <<= 1) {
        for (u32 j = kk >> 1; j > 0; j >>= 1) {
            u32 i = (u32)tid;
            if (i < m) {
                u32 ixj = i ^ j;
                if (ixj > i) {
                    u64 x = ebuf[i], y = ebuf[ixj];
                    bool up = ((i & kk) == 0);
                    if (up ? (x > y) : (x < y)) {
                        ebuf[i] = y; ebuf[ixj] = x;
                        u32 t = eidx[i]; eidx[i] = eidx[ixj]; eidx[ixj] = t;
                    }
                }
            }
            __syncthreads();
        }
    }
    if (tid < MAXDET && tid < n) {
        u64 comp = ebuf[tid];
        if (comp != ~0ULL) {
            const uint4* e = (const uint4*)(keptbuf + (size_t)eidx[tid] * 8);
            uint4 a = e[0], b = e[1];
            float* o = out + tid * 7;
            o[0] = 0.0f;
            o[1] = __uint_as_float(a.z); o[2] = __uint_as_float(a.w);
            o[3] = __uint_as_float(b.x); o[4] = __uint_as_float(b.y);
            o[5] = __uint_as_float(b.z);
            o[6] = (float)(((u32)comp) >> 9);   // low word = c*512+pos -> class
        }
    }
}

extern "C" void kernel_launch(void* const* d_in, const int* in_sizes, int n_in,
                              void* d_out, int out_size, void* d_ws, size_t ws_size,
                              hipStream_t stream) {
    const float* reg     = (const float*)d_in[1];
    const float* cls     = (const float*)d_in[2];
    const float* anchors = (const float*)d_in[3];
    float* out = (float*)d_out;

    char* ws = (char*)d_ws;
    size_t off = 0;
    auto alloc = [&](size_t bytes) -> void* {
        void* p = ws + off;
        off = (off + bytes + 255) & ~(size_t)255;
        return p;
    };
    u32*    keysT   = (u32*)   alloc((size_t)C_N * A_N * sizeof(u32));          // 39.8 MB
    float4* boxes   = (float4*)alloc((size_t)A_N * sizeof(float4));             // 1.77 MB
    u64*    candbuf = (u64*)   alloc((size_t)C_N * CAND_N * sizeof(u64));       // 1.47 MB
    u32*    keptbuf = (u32*)   alloc((size_t)C_N * KEEP_CAP * 8 * sizeof(u32)); // 288 KB
    u32*    cnt2    = (u32*)   alloc((size_t)C_N * sizeof(u32));
    float4* sbox    = (float4*)alloc((size_t)C_N * KCAND * sizeof(float4));     // 737 KB
    float*  ssc     = (float*) alloc((size_t)C_N * KCAND * sizeof(float));      // 184 KB
    u32*    gmask   = (u32*)   alloc((size_t)C_N * KCAND * 16 * sizeof(u32));   // 2.95 MB
    (void)ws_size;

    prep_kernel<<<T_BLKS, 256, 0, stream>>>(cls, keysT);
    select_kernel<<<S_BLKS + D_BLKS, 256, 0, stream>>>(keysT, anchors, reg, boxes, candbuf);
    sort_kernel<<<C_N, 1024, 0, stream>>>(candbuf, boxes, sbox, ssc);
    mask_kernel<<<C_N * STRIPS, 256, 0, stream>>>(sbox, gmask);
    scan_kernel<<<C_N, 512, 0, stream>>>(gmask, sbox, ssc, keptbuf, cnt2);
    final_kernel<<<1, 1024, 0, stream>>>(keptbuf, cnt2, out);
}

// Round 2
// 210.033 us; speedup vs baseline: 1.0759x; 1.0759x over previous
//
#include <hip/hip_runtime.h>
#include <math.h>

// EfficientDet post-processing v13 (4 launches).
// prep(transpose vec4) -> select(512-thr, u16-hist sorted top-512 per (class,slice) + decode)
// -> nms(resume-bitonic + ballot wave-per-row IoU mask + greedy scan + compact, fused)
// -> final(hist-select top-100 over <=9000 kept entries).

#define A_N   110484
#define C_N   90
#define KCAND 512
#define NBINS 8192        // 13-bit histogram bins (key >> 19)
#define KSH   19
#define MAXDET 100
#define IMG_F 768.0f
#define THRESH 0.05f
#define NS    4                                   // slices per class
#define VTOT  (A_N / 4)                           // 27621 vec4 units
#define VS4   ((VTOT + NS - 1) / NS)              // 6906
#define SL_CAP 1024                               // per-slice candidate cap
#define CAND_N (NS * KCAND)                       // 2048 per class (sorted runs)
#define KEEP_CAP 100
#define T_BLKS ((A_N + 63) / 64)                  // 1727 transpose blocks
#define S_BLKS (C_N * NS)                         // 360 select blocks
#define SEL_T 512
#define D_BLKS ((A_N + SEL_T - 1) / SEL_T)        // 216 decode blocks
#define FCAP  512                                 // final collect capacity

typedef unsigned int u32;
typedef unsigned long long u64;

__device__ __forceinline__ u32 fkey(float f) {
    u32 u = __float_as_uint(f);
    return (u & 0x80000000u) ? ~u : (u | 0x80000000u);
}
__device__ __forceinline__ float unfkey(u32 k) {
    u32 u = (k & 0x80000000u) ? (k ^ 0x80000000u) : ~k;
    return __uint_as_float(u);
}
__device__ __forceinline__ u64 shflx64(u64 v, int m) {
    u32 lo = (u32)__shfl_xor((int)(u32)v, m, 64);
    u32 hi = (u32)__shfl_xor((int)(v >> 32), m, 64);
    return ((u64)hi << 32) | lo;
}

// ------- Stage 1: transpose (sigmoid->key, vec4 loads) -------
__global__ __launch_bounds__(256)
void prep_kernel(const float* __restrict__ cls,
                 u32* __restrict__ keysT) {
    __shared__ u32 tile[64 * 91];   // 23.3 KB, stride 91 (odd) = conflict-free
    const int a0 = blockIdx.x * 64;
    const int lim = min(64, A_N - a0);           // 64 or 20; lim*90 % 4 == 0
    const int n4 = (lim * C_N) >> 2;
    const float4* src4 = (const float4*)(cls + (size_t)a0 * C_N);
    for (int i4 = threadIdx.x; i4 < n4; i4 += 256) {
        float4 x4 = src4[i4];
        const u32 base = (u32)(4 * i4);
        float xs[4] = { x4.x, x4.y, x4.z, x4.w };
        #pragma unroll
        for (int k = 0; k < 4; ++k) {
            u32 i = base + k;
            u32 aa = i / C_N, c = i % C_N;
            float s = 1.0f / (1.0f + expf(-xs[k]));
            tile[aa * 91 + c] = fkey(s);
        }
    }
    __syncthreads();
    for (int j = threadIdx.x; j < C_N * 64; j += 256) {
        int c = j >> 6, aa = j & 63;
        if (aa < lim)
            keysT[(size_t)c * A_N + a0 + aa] = tile[aa * 91 + c];
    }
}

// ---- Stage 2: per-(class,slice) exact sorted top-512 (+ decode blocks) ----
// 512 threads, u16-packed hist (16 KB), 4-wide unrolled global loads.
__global__ __launch_bounds__(SEL_T)
void select_kernel(const u32* __restrict__ keysT,
                   const float* __restrict__ anchors,
                   const float* __restrict__ reg,
                   float4* __restrict__ boxes,
                   u64* __restrict__ candbuf) {
    __shared__ u32 hist[NBINS / 2];   // 16 KB, two u16 counters per word
    __shared__ u32 csum[SEL_T];       // 2 KB
    __shared__ u64 lbuf[SL_CAP];      // 8 KB
    __shared__ u32 sPv;
    __shared__ int lcnt;
    const int tid = threadIdx.x;

    if (blockIdx.x >= S_BLKS) {    // decode blocks
        int a = (blockIdx.x - S_BLKS) * SEL_T + tid;
        if (a < A_N) {
            float4 an = ((const float4*)anchors)[a];
            float4 dl = ((const float4*)reg)[a];
            float wa = an.z - an.x, ha = an.w - an.y;
            float cx = an.x + 0.5f * wa + dl.x * wa;
            float cy = an.y + 0.5f * ha + dl.y * ha;
            float w = expf(dl.z) * wa;
            float h = expf(dl.w) * ha;
            float4 o;
            o.x = fminf(fmaxf(cx - 0.5f * w, 0.0f), IMG_F);
            o.y = fminf(fmaxf(cy - 0.5f * h, 0.0f), IMG_F);
            o.z = fminf(fmaxf(cx + 0.5f * w, 0.0f), IMG_F);
            o.w = fminf(fmaxf(cy + 0.5f * h, 0.0f), IMG_F);
            boxes[a] = o;
        }
        return;
    }
    const int c = blockIdx.x >> 2, s = blockIdx.x & 3;
    const int lo = s * VS4, hiEnd = min(VTOT, lo + VS4);
    const uint4* kv = (const uint4*)(keysT + (size_t)c * A_N);

    for (int i = tid; i < NBINS / 2; i += SEL_T) hist[i] = 0;
    if (tid == 0) { sPv = 0; lcnt = 0; }
    __syncthreads();

    // --- pass 1: histogram (counts packed: even bin = low half, odd = high) ---
    #define HACC(K) do { \
        u32 b0 = (K).x >> KSH, b1 = (K).y >> KSH, b2 = (K).z >> KSH, b3 = (K).w >> KSH; \
        atomicAdd(&hist[b0 >> 1], 1u << ((b0 & 1) << 4)); \
        atomicAdd(&hist[b1 >> 1], 1u << ((b1 & 1) << 4)); \
        atomicAdd(&hist[b2 >> 1], 1u << ((b2 & 1) << 4)); \
        atomicAdd(&hist[b3 >> 1], 1u << ((b3 & 1) << 4)); } while (0)
    {
        int i = lo + tid;
        for (; i + 3 * SEL_T < hiEnd; i += 4 * SEL_T) {
            uint4 ka = kv[i], kb = kv[i + SEL_T], kc = kv[i + 2 * SEL_T], kd = kv[i + 3 * SEL_T];
            HACC(ka); HACC(kb); HACC(kc); HACC(kd);
        }
        for (; i < hiEnd; i += SEL_T) { uint4 ka = kv[i]; HACC(ka); }
    }
    __syncthreads();

    // --- chunk sums (16 bins = 8 words per thread, descending), rotated reads ---
    u32 own = 0;
    {
        const int wb = (NBINS / 2) - 8 - 8 * tid;   // lowest word of my chunk
        const int g = (tid >> 2) & 7;               // rotation -> 2 lanes/bank
        #pragma unroll
        for (int jj = 0; jj < 8; ++jj) {
            u32 v = hist[wb + ((g + jj) & 7)];
            own += (v & 0xffffu) + (v >> 16);
        }
    }
    csum[tid] = own;
    __syncthreads();
    for (int off = 1; off < SEL_T; off <<= 1) {
        u32 v = csum[tid];
        u32 a = (tid >= off) ? csum[tid - off] : 0u;
        __syncthreads();
        csum[tid] = v + a;
        __syncthreads();
    }
    const u32 incl = csum[tid], excl = incl - own;
    if (excl < (u32)KCAND && incl >= (u32)KCAND) {
        u32 cum = excl;
        const int hb = NBINS - 1 - 16 * tid;
        for (int j = 0; j < 16; ++j) {
            int b = hb - j;
            u32 v = hist[b >> 1];
            u32 cnt = (b & 1) ? (v >> 16) : (v & 0xffffu);
            if (cum + cnt >= (u32)KCAND) { sPv = (u32)b; break; }
            cum += cnt;
        }
    }
    __syncthreads();
    const u32 P = sPv;

    // --- pass 2: collect candidates >= pivot bin ---
    #define CACC(K, BASE) do { \
        if (((K).x >> KSH) >= P) { int p = atomicAdd(&lcnt, 1); if (p < SL_CAP) lbuf[p] = (((u64)(~(K).x)) << 32) | (u32)(BASE); } \
        if (((K).y >> KSH) >= P) { int p = atomicAdd(&lcnt, 1); if (p < SL_CAP) lbuf[p] = (((u64)(~(K).y)) << 32) | (u32)((BASE) + 1); } \
        if (((K).z >> KSH) >= P) { int p = atomicAdd(&lcnt, 1); if (p < SL_CAP) lbuf[p] = (((u64)(~(K).z)) << 32) | (u32)((BASE) + 2); } \
        if (((K).w >> KSH) >= P) { int p = atomicAdd(&lcnt, 1); if (p < SL_CAP) lbuf[p] = (((u64)(~(K).w)) << 32) | (u32)((BASE) + 3); } } while (0)
    {
        int i = lo + tid;
        for (; i + 3 * SEL_T < hiEnd; i += 4 * SEL_T) {
            uint4 ka = kv[i], kb = kv[i + SEL_T], kc = kv[i + 2 * SEL_T], kd = kv[i + 3 * SEL_T];
            CACC(ka, 4 * i); CACC(kb, 4 * (i + SEL_T)); CACC(kc, 4 * (i + 2 * SEL_T)); CACC(kd, 4 * (i + 3 * SEL_T));
        }
        for (; i < hiEnd; i += SEL_T) { uint4 ka = kv[i]; CACC(ka, 4 * i); }
    }
    __syncthreads();
    const int n = min(lcnt, SL_CAP);   // n >= 512 guaranteed by pivot
    for (int q = tid; q < SL_CAP; q += SEL_T) if (q >= n) lbuf[q] = ~0ULL;
    __syncthreads();

    // --- bitonic 1024 sort: 8 waves x (2 regs x 64 lanes) ---
    {
        const int l = tid & 63, w = tid >> 6;
        const int i0 = 128 * w + l, i1 = i0 + 64;
        u64 v0 = lbuf[i0], v1 = lbuf[i1];
        __syncthreads();
        #pragma unroll
        for (u32 kk = 2; kk <= 1024; kk <<= 1) {
            #pragma unroll
            for (u32 j = kk >> 1; j > 0; j >>= 1) {
                if (j >= 128) {
                    lbuf[i0] = v0; lbuf[i1] = v1;
                    __syncthreads();
                    u64 w0 = lbuf[i0 ^ j], w1 = lbuf[i1 ^ j];
                    bool m0 = (((i0 & j) == 0) == ((i0 & kk) == 0));
                    bool m1 = (((i1 & j) == 0) == ((i1 & kk) == 0));
                    v0 = m0 ? (v0 < w0 ? v0 : w0) : (v0 > w0 ? v0 : w0);
                    v1 = m1 ? (v1 < w1 ? v1 : w1) : (v1 > w1 ? v1 : w1);
                    __syncthreads();
                } else if (j == 64) {
                    bool up = ((i0 & kk) == 0);
                    u64 mn = v0 < v1 ? v0 : v1, mx = v0 < v1 ? v1 : v0;
                    v0 = up ? mn : mx; v1 = up ? mx : mn;
                } else {
                    u64 w0 = shflx64(v0, (int)j), w1 = shflx64(v1, (int)j);
                    bool m0 = (((i0 & j) == 0) == ((i0 & kk) == 0));
                    bool m1 = (((i1 & j) == 0) == ((i1 & kk) == 0));
                    v0 = m0 ? (v0 < w0 ? v0 : w0) : (v0 > w0 ? v0 : w0);
                    v1 = m1 ? (v1 < w1 ? v1 : w1) : (v1 > w1 ? v1 : w1);
                }
            }
        }
        if (w < 4) {   // i0, i1 in [0, 512)
            u64* cb = candbuf + (size_t)c * CAND_N + (size_t)s * KCAND;
            const bool rev = (s & 1);
            int d0 = rev ? (KCAND - 1 - i0) : i0;
            int d1 = rev ? (KCAND - 1 - i1) : i1;
            cb[d0] = v0; cb[d1] = v1;
        }
    }
}

// ---- Stage 3: fused resume-bitonic(2048) + ballot IoU mask + scan + compact ----
__global__ __launch_bounds__(1024)
void nms_kernel(const u64* __restrict__ candbuf,
                const float4* __restrict__ boxes,
                u32* __restrict__ keptbuf, u32* __restrict__ cnt2) {
    __shared__ u64 sortbuf[2][CAND_N];     // 32 KB; reused as bmask after sort
    __shared__ float bxx[KCAND], byy[KCAND], bzz[KCAND], bww[KCAND];
    __shared__ float ar[KCAND], sc[KCAND];
    __shared__ u32 keepf[16], wbase[17];
    u32* bmask = (u32*)&sortbuf[0][0];     // 512 rows x 16 words = 32 KB
    const int c = blockIdx.x, tid = threadIdx.x;
    const int l = tid & 63, w = tid >> 6;
    const int i0 = 128 * w + l, i1 = i0 + 64;

    // input: 4 sorted runs of 512, alternating asc/desc = post-stage-512 state
    const u64* cb = candbuf + (size_t)c * CAND_N;
    u64 v0 = cb[i0], v1 = cb[i1];
    int p = 0;
    #pragma unroll
    for (u32 kk = 1024; kk <= (u32)CAND_N; kk <<= 1) {
        #pragma unroll
        for (u32 j = kk >> 1; j > 0; j >>= 1) {
            if (j >= 128) {
                sortbuf[p][i0] = v0; sortbuf[p][i1] = v1;
                __syncthreads();
                u64 w0 = sortbuf[p][i0 ^ j], w1 = sortbuf[p][i1 ^ j];
                bool m0 = (((i0 & j) == 0) == ((i0 & kk) == 0));
                bool m1 = (((i1 & j) == 0) == ((i1 & kk) == 0));
                v0 = m0 ? (v0 < w0 ? v0 : w0) : (v0 > w0 ? v0 : w0);
                v1 = m1 ? (v1 < w1 ? v1 : w1) : (v1 > w1 ? v1 : w1);
                p ^= 1;
            } else if (j == 64) {
                bool up = ((i0 & kk) == 0);
                u64 mn = v0 < v1 ? v0 : v1, mx = v0 < v1 ? v1 : v0;
                v0 = up ? mn : mx; v1 = up ? mx : mn;
            } else {
                u64 w0 = shflx64(v0, (int)j), w1 = shflx64(v1, (int)j);
                bool m0 = (((i0 & j) == 0) == ((i0 & kk) == 0));
                bool m1 = (((i1 & j) == 0) == ((i1 & kk) == 0));
                v0 = m0 ? (v0 < w0 ? v0 : w0) : (v0 > w0 ? v0 : w0);
                v1 = m1 ? (v1 < w1 ? v1 : w1) : (v1 > w1 ? v1 : w1);
            }
        }
    }
    __syncthreads();   // sort done in registers; sortbuf free for bmask

    // --- top-512 -> SoA ---
    if (w < 4) {   // i0,i1 < 512
        u32 idx0 = (u32)v0, key0 = ~((u32)(v0 >> 32));
        u32 idx1 = (u32)v1, key1 = ~((u32)(v1 >> 32));
        sc[i0] = unfkey(key0); sc[i1] = unfkey(key1);
        float4 b0 = boxes[idx0], b1 = boxes[idx1];
        bxx[i0] = b0.x; byy[i0] = b0.y; bzz[i0] = b0.z; bww[i0] = b0.w;
        bxx[i1] = b1.x; byy[i1] = b1.y; bzz[i1] = b1.z; bww[i1] = b1.w;
        ar[i0] = (b0.z - b0.x) * (b0.w - b0.y);
        ar[i1] = (b1.z - b1.x) * (b1.w - b1.y);
    }
    if (tid < 16) keepf[tid] = 0;
    __syncthreads();

    // --- IoU mask: wave-per-row, ballot bit-pack (writes every row word) ---
    for (int r = w; r < KCAND; r += 16) {
        const float bix = bxx[r], biy = byy[r], biz = bzz[r], biw = bww[r];
        const float ai = ar[r];
        const int q0 = (r + 1) >> 6;
        u32* row = bmask + r * 16;
        if (l < 2 * q0) row[l] = 0;                       // words below diagonal
        for (int q = q0; q < 8; ++q) {                    // wave-uniform bounds
            const int j = q * 64 + l;                     // consecutive lanes
            float xx1 = fmaxf(bix, bxx[j]), yy1 = fmaxf(biy, byy[j]);
            float xx2 = fminf(biz, bzz[j]), yy2 = fminf(biw, bww[j]);
            float inter = fmaxf(xx2 - xx1, 0.0f) * fmaxf(yy2 - yy1, 0.0f);
            float uni = ai + ar[j] - inter + 1e-8f;       // identical expr order
            bool sup = (j > r) && (inter > 0.5f * uni);
            u64 bal = __ballot(sup);
            if (l == 0)      row[2 * q]     = (u32)bal;
            else if (l == 1) row[2 * q + 1] = (u32)(bal >> 32);
        }
    }
    __syncthreads();

    // --- greedy scan, wave 0; register-pipelined rows + readlane chain ---
    if (tid < 64) {
        const int lw = tid & 15;
        u32 removed = 0, keepw = 0;
        u32 rA[8], rB[8]; float sA[8], sB[8];
        #pragma unroll
        for (int k = 0; k < 8; ++k) { rA[k] = bmask[k * 16 + lw]; sA[k] = sc[k]; }
        #pragma unroll 1
        for (int ch = 0; ch < 64; ch += 2) {
            const int tb1 = (ch + 1) * 8;
            #pragma unroll
            for (int k = 0; k < 8; ++k) { rB[k] = bmask[(tb1 + k) * 16 + lw]; sB[k] = sc[tb1 + k]; }
            {
                const int tb = ch * 8;
                #pragma unroll
                for (int k = 0; k < 8; ++k) {
                    const int t = tb + k;
                    u32 rw = (u32)__builtin_amdgcn_readlane((int)removed, t >> 5);
                    bool d = (sA[k] > THRESH) && (((rw >> (t & 31)) & 1u) == 0u);
                    removed |= d ? rA[k] : 0u;
                    keepw |= (d && (tid == (t >> 5))) ? (1u << (t & 31)) : 0u;
                }
            }
            const int tb2 = (ch + 2 < 64) ? (ch + 2) * 8 : 0;
            #pragma unroll
            for (int k = 0; k < 8; ++k) { rA[k] = bmask[(tb2 + k) * 16 + lw]; sA[k] = sc[tb2 + k]; }
            {
                #pragma unroll
                for (int k = 0; k < 8; ++k) {
                    const int t = tb1 + k;
                    u32 rw = (u32)__builtin_amdgcn_readlane((int)removed, t >> 5);
                    bool d = (sB[k] > THRESH) && (((rw >> (t & 31)) & 1u) == 0u);
                    removed |= d ? rB[k] : 0u;
                    keepw |= (d && (tid == (t >> 5))) ? (1u << (t & 31)) : 0u;
                }
            }
        }
        if (tid < 16) keepf[tid] = keepw;
    }
    __syncthreads();

    // --- compact kept (sorted order) to keptbuf, cap 100/class ---
    if (tid == 0) {
        u32 t = 0;
        for (int q = 0; q < 16; ++q) { wbase[q] = t; t += __popc(keepf[q]); }
        wbase[16] = t;
        cnt2[c] = (t < (u32)KEEP_CAP) ? t : (u32)KEEP_CAP;
    }
    __syncthreads();
    if (tid < KCAND) {
        u32 word = keepf[tid >> 5];
        u32 bit = (u32)tid & 31u;
        if ((word >> bit) & 1u) {
            u32 rank = wbase[tid >> 5] + __popc(word & ((1u << bit) - 1u));
            if (rank < (u32)KEEP_CAP) {
                float s = sc[tid];
                uint4 a, b;
                a.x = ~fkey(s);
                a.y = (u32)(c * KCAND + tid);
                a.z = __float_as_uint(bxx[tid]);
                a.w = __float_as_uint(byy[tid]);
                b.x = __float_as_uint(bzz[tid]);
                b.y = __float_as_uint(bww[tid]);
                b.z = __float_as_uint(s);
                b.w = 0u;
                uint4* e = (uint4*)(keptbuf + ((size_t)c * KEEP_CAP + rank) * 8);
                e[0] = a; e[1] = b;
            }
        }
    }
}

// ---- Stage 4: global top-100 via hist-select over <=9000 kept entries ----
__global__ __launch_bounds__(1024)
void final_kernel(const u32* __restrict__ keptbuf, const u32* __restrict__ cnt2,
                  float* __restrict__ out) {
    __shared__ u32 hist[NBINS];    // 32 KB
    __shared__ u32 csum[1024];     // 4 KB
    __shared__ u64 ebuf[FCAP];     // 4 KB keys
    __shared__ u32 eidx[FCAP];     // 2 KB payload (keptbuf entry index)
    __shared__ u32 scnt[C_N];
    __shared__ u32 sP;
    __shared__ int sN;
    const int tid = threadIdx.x;
    const int TOT = C_N * KEEP_CAP;   // 9000

    for (int i = tid; i < MAXDET * 7; i += 1024) out[i] = 0.0f;
    for (int i = tid; i < NBINS; i += 1024) hist[i] = 0;
    if (tid < C_N) scnt[tid] = cnt2[tid];
    if (tid == 0) { sN = 0; sP = NBINS - 1; }
    __syncthreads();

    // hist over composite high word (smaller = better -> ascending pivot)
    for (int i = tid; i < TOT; i += 1024) {
        u32 c = (u32)i / KEEP_CAP, pp = (u32)i % KEEP_CAP;
        if (pp < scnt[c]) {
            u32 khi = keptbuf[(size_t)i * 8];   // a.x = ~fkey(s)
            atomicAdd(&hist[khi >> KSH], 1u);
        }
    }
    __syncthreads();
    // ascending chunk sums (8 bins each) + Hillis-Steele scan
    u32 own = 0; const int lo = 8 * tid;
    #pragma unroll
    for (int j = 0; j < 8; ++j) own += hist[lo + j];
    csum[tid] = own;
    __syncthreads();
    for (int off = 1; off < 1024; off <<= 1) {
        u32 v = csum[tid];
        u32 a = (tid >= off) ? csum[tid - off] : 0u;
        __syncthreads();
        csum[tid] = v + a;
        __syncthreads();
    }
    const u32 incl = csum[tid], excl = incl - own;
    if (excl < (u32)MAXDET && incl >= (u32)MAXDET) {
        u32 cum = excl;
        for (int j = 0; j < 8; ++j) {
            u32 h = hist[lo + j];
            if (cum + h >= (u32)MAXDET) { sP = (u32)(lo + j); break; }
            cum += h;
        }
    }
    __syncthreads();
    const u32 P = sP;
    // collect entries with bin <= P
    for (int i = tid; i < TOT; i += 1024) {
        u32 c = (u32)i / KEEP_CAP, pp = (u32)i % KEEP_CAP;
        if (pp < scnt[c]) {
            const uint2 v2 = *((const uint2*)(keptbuf + (size_t)i * 8));
            if ((v2.x >> KSH) <= P) {
                int p = atomicAdd(&sN, 1);
                if (p < FCAP) {
                    ebuf[p] = ((u64)v2.x << 32) | v2.y;
                    eidx[p] = (u32)i;
                }
            }
        }
    }
    __syncthreads();
    const int n = min(sN, FCAP);
    u32 m = 128; while ((int)m < n) m <<= 1;   // 128..512, uniform
    for (int i = tid; i < (int)m; i += 1024) if (i >= n) ebuf[i] = ~0ULL;
    __syncthreads();
    // bitonic sort (key ebuf asc, payload eidx follows)
    for (u32 kk = 2; kk <= m; kk <<= 1) {
        for (u32 j = kk >> 1; j > 0; j >>= 1) {
            u32 i = (u32)tid;
            if (i < m) {
                u32 ixj = i ^ j;
                if (ixj > i) {
                    u64 x = ebuf[i], y = ebuf[ixj];
                    bool up = ((i & kk) == 0);
                    if (up ? (x > y) : (x < y)) {
                        ebuf[i] = y; ebuf[ixj] = x;
                        u32 t = eidx[i]; eidx[i] = eidx[ixj]; eidx[ixj] = t;
                    }
                }
            }
            __syncthreads();
        }
    }
    if (tid < MAXDET && tid < n) {
        u64 comp = ebuf[tid];
        if (comp != ~0ULL) {
            const uint4* e = (const uint4*)(keptbuf + (size_t)eidx[tid] * 8);
            uint4 a = e[0], b = e[1];
            float* o = out + tid * 7;
            o[0] = 0.0f;
            o[1] = __uint_as_float(a.z); o[2] = __uint_as_float(a.w);
            o[3] = __uint_as_float(b.x); o[4] = __uint_as_float(b.y);
            o[5] = __uint_as_float(b.z);
            o[6] = (float)(((u32)comp) >> 9);   // low word = c*512+pos -> class
        }
    }
}

extern "C" void kernel_launch(void* const* d_in, const int* in_sizes, int n_in,
                              void* d_out, int out_size, void* d_ws, size_t ws_size,
                              hipStream_t stream) {
    const float* reg     = (const float*)d_in[1];
    const float* cls     = (const float*)d_in[2];
    const float* anchors = (const float*)d_in[3];
    float* out = (float*)d_out;

    char* ws = (char*)d_ws;
    size_t off = 0;
    auto alloc = [&](size_t bytes) -> void* {
        void* p = ws + off;
        off = (off + bytes + 255) & ~(size_t)255;
        return p;
    };
    u32*    keysT   = (u32*)   alloc((size_t)C_N * A_N * sizeof(u32));          // 39.8 MB
    float4* boxes   = (float4*)alloc((size_t)A_N * sizeof(float4));             // 1.77 MB
    u64*    candbuf = (u64*)   alloc((size_t)C_N * CAND_N * sizeof(u64));       // 1.47 MB
    u32*    keptbuf = (u32*)   alloc((size_t)C_N * KEEP_CAP * 8 * sizeof(u32)); // 288 KB
    u32*    cnt2    = (u32*)   alloc((size_t)C_N * sizeof(u32));
    (void)ws_size;

    prep_kernel<<<T_BLKS, 256, 0, stream>>>(cls, keysT);
    select_kernel<<<S_BLKS + D_BLKS, SEL_T, 0, stream>>>(keysT, anchors, reg, boxes, candbuf);
    nms_kernel<<<C_N, 1024, 0, stream>>>(candbuf, boxes, keptbuf, cnt2);
    final_kernel<<<1, 1024, 0, stream>>>(keptbuf, cnt2, out);
}

// Round 3
// 206.480 us; speedup vs baseline: 1.0944x; 1.0172x over previous
//
#include <hip/hip_runtime.h>
#include <math.h>

// EfficientDet post-processing v14 (4 launches).
// prep(transpose vec4) -> select(512-thr, u16-hist sorted top-512 per (class,slice) + decode)
// -> nms(resume-bitonic + register-resident ballot IoU mask + greedy scan + compact, fused)
// -> final(hist-select top-100 over <=9000 kept entries).
// v14: mask phase preloads column boxes into 40 VGPRs (j = q*64+l invariant
// across rows) -> LDS instrs in mask drop ~10.2K -> ~3K per block.

#define A_N   110484
#define C_N   90
#define KCAND 512
#define NBINS 8192        // 13-bit histogram bins (key >> 19)
#define KSH   19
#define MAXDET 100
#define IMG_F 768.0f
#define THRESH 0.05f
#define NS    4                                   // slices per class
#define VTOT  (A_N / 4)                           // 27621 vec4 units
#define VS4   ((VTOT + NS - 1) / NS)              // 6906
#define SL_CAP 1024                               // per-slice candidate cap
#define CAND_N (NS * KCAND)                       // 2048 per class (sorted runs)
#define KEEP_CAP 100
#define T_BLKS ((A_N + 63) / 64)                  // 1727 transpose blocks
#define S_BLKS (C_N * NS)                         // 360 select blocks
#define SEL_T 512
#define D_BLKS ((A_N + SEL_T - 1) / SEL_T)        // 216 decode blocks
#define FCAP  512                                 // final collect capacity

typedef unsigned int u32;
typedef unsigned long long u64;

__device__ __forceinline__ u32 fkey(float f) {
    u32 u = __float_as_uint(f);
    return (u & 0x80000000u) ? ~u : (u | 0x80000000u);
}
__device__ __forceinline__ float unfkey(u32 k) {
    u32 u = (k & 0x80000000u) ? (k ^ 0x80000000u) : ~k;
    return __uint_as_float(u);
}
__device__ __forceinline__ u64 shflx64(u64 v, int m) {
    u32 lo = (u32)__shfl_xor((int)(u32)v, m, 64);
    u32 hi = (u32)__shfl_xor((int)(v >> 32), m, 64);
    return ((u64)hi << 32) | lo;
}

// ------- Stage 1: transpose (sigmoid->key, vec4 loads) -------
__global__ __launch_bounds__(256)
void prep_kernel(const float* __restrict__ cls,
                 u32* __restrict__ keysT) {
    __shared__ u32 tile[64 * 91];   // 23.3 KB, stride 91 (odd) = conflict-free
    const int a0 = blockIdx.x * 64;
    const int lim = min(64, A_N - a0);           // 64 or 20; lim*90 % 4 == 0
    const int n4 = (lim * C_N) >> 2;
    const float4* src4 = (const float4*)(cls + (size_t)a0 * C_N);
    for (int i4 = threadIdx.x; i4 < n4; i4 += 256) {
        float4 x4 = src4[i4];
        const u32 base = (u32)(4 * i4);
        float xs[4] = { x4.x, x4.y, x4.z, x4.w };
        #pragma unroll
        for (int k = 0; k < 4; ++k) {
            u32 i = base + k;
            u32 aa = i / C_N, c = i % C_N;
            float s = 1.0f / (1.0f + expf(-xs[k]));
            tile[aa * 91 + c] = fkey(s);
        }
    }
    __syncthreads();
    for (int j = threadIdx.x; j < C_N * 64; j += 256) {
        int c = j >> 6, aa = j & 63;
        if (aa < lim)
            keysT[(size_t)c * A_N + a0 + aa] = tile[aa * 91 + c];
    }
}

// ---- Stage 2: per-(class,slice) exact sorted top-512 (+ decode blocks) ----
// 512 threads, u16-packed hist (16 KB), 4-wide unrolled global loads.
__global__ __launch_bounds__(SEL_T)
void select_kernel(const u32* __restrict__ keysT,
                   const float* __restrict__ anchors,
                   const float* __restrict__ reg,
                   float4* __restrict__ boxes,
                   u64* __restrict__ candbuf) {
    __shared__ u32 hist[NBINS / 2];   // 16 KB, two u16 counters per word
    __shared__ u32 csum[SEL_T];       // 2 KB
    __shared__ u64 lbuf[SL_CAP];      // 8 KB
    __shared__ u32 sPv;
    __shared__ int lcnt;
    const int tid = threadIdx.x;

    if (blockIdx.x >= S_BLKS) {    // decode blocks
        int a = (blockIdx.x - S_BLKS) * SEL_T + tid;
        if (a < A_N) {
            float4 an = ((const float4*)anchors)[a];
            float4 dl = ((const float4*)reg)[a];
            float wa = an.z - an.x, ha = an.w - an.y;
            float cx = an.x + 0.5f * wa + dl.x * wa;
            float cy = an.y + 0.5f * ha + dl.y * ha;
            float w = expf(dl.z) * wa;
            float h = expf(dl.w) * ha;
            float4 o;
            o.x = fminf(fmaxf(cx - 0.5f * w, 0.0f), IMG_F);
            o.y = fminf(fmaxf(cy - 0.5f * h, 0.0f), IMG_F);
            o.z = fminf(fmaxf(cx + 0.5f * w, 0.0f), IMG_F);
            o.w = fminf(fmaxf(cy + 0.5f * h, 0.0f), IMG_F);
            boxes[a] = o;
        }
        return;
    }
    const int c = blockIdx.x >> 2, s = blockIdx.x & 3;
    const int lo = s * VS4, hiEnd = min(VTOT, lo + VS4);
    const uint4* kv = (const uint4*)(keysT + (size_t)c * A_N);

    for (int i = tid; i < NBINS / 2; i += SEL_T) hist[i] = 0;
    if (tid == 0) { sPv = 0; lcnt = 0; }
    __syncthreads();

    // --- pass 1: histogram (counts packed: even bin = low half, odd = high) ---
    #define HACC(K) do { \
        u32 b0 = (K).x >> KSH, b1 = (K).y >> KSH, b2 = (K).z >> KSH, b3 = (K).w >> KSH; \
        atomicAdd(&hist[b0 >> 1], 1u << ((b0 & 1) << 4)); \
        atomicAdd(&hist[b1 >> 1], 1u << ((b1 & 1) << 4)); \
        atomicAdd(&hist[b2 >> 1], 1u << ((b2 & 1) << 4)); \
        atomicAdd(&hist[b3 >> 1], 1u << ((b3 & 1) << 4)); } while (0)
    {
        int i = lo + tid;
        for (; i + 3 * SEL_T < hiEnd; i += 4 * SEL_T) {
            uint4 ka = kv[i], kb = kv[i + SEL_T], kc = kv[i + 2 * SEL_T], kd = kv[i + 3 * SEL_T];
            HACC(ka); HACC(kb); HACC(kc); HACC(kd);
        }
        for (; i < hiEnd; i += SEL_T) { uint4 ka = kv[i]; HACC(ka); }
    }
    __syncthreads();

    // --- chunk sums (16 bins = 8 words per thread, descending), rotated reads ---
    u32 own = 0;
    {
        const int wb = (NBINS / 2) - 8 - 8 * tid;   // lowest word of my chunk
        const int g = (tid >> 2) & 7;               // rotation -> 2 lanes/bank
        #pragma unroll
        for (int jj = 0; jj < 8; ++jj) {
            u32 v = hist[wb + ((g + jj) & 7)];
            own += (v & 0xffffu) + (v >> 16);
        }
    }
    csum[tid] = own;
    __syncthreads();
    for (int off = 1; off < SEL_T; off <<= 1) {
        u32 v = csum[tid];
        u32 a = (tid >= off) ? csum[tid - off] : 0u;
        __syncthreads();
        csum[tid] = v + a;
        __syncthreads();
    }
    const u32 incl = csum[tid], excl = incl - own;
    if (excl < (u32)KCAND && incl >= (u32)KCAND) {
        u32 cum = excl;
        const int hb = NBINS - 1 - 16 * tid;
        for (int j = 0; j < 16; ++j) {
            int b = hb - j;
            u32 v = hist[b >> 1];
            u32 cnt = (b & 1) ? (v >> 16) : (v & 0xffffu);
            if (cum + cnt >= (u32)KCAND) { sPv = (u32)b; break; }
            cum += cnt;
        }
    }
    __syncthreads();
    const u32 P = sPv;

    // --- pass 2: collect candidates >= pivot bin ---
    #define CACC(K, BASE) do { \
        if (((K).x >> KSH) >= P) { int p = atomicAdd(&lcnt, 1); if (p < SL_CAP) lbuf[p] = (((u64)(~(K).x)) << 32) | (u32)(BASE); } \
        if (((K).y >> KSH) >= P) { int p = atomicAdd(&lcnt, 1); if (p < SL_CAP) lbuf[p] = (((u64)(~(K).y)) << 32) | (u32)((BASE) + 1); } \
        if (((K).z >> KSH) >= P) { int p = atomicAdd(&lcnt, 1); if (p < SL_CAP) lbuf[p] = (((u64)(~(K).z)) << 32) | (u32)((BASE) + 2); } \
        if (((K).w >> KSH) >= P) { int p = atomicAdd(&lcnt, 1); if (p < SL_CAP) lbuf[p] = (((u64)(~(K).w)) << 32) | (u32)((BASE) + 3); } } while (0)
    {
        int i = lo + tid;
        for (; i + 3 * SEL_T < hiEnd; i += 4 * SEL_T) {
            uint4 ka = kv[i], kb = kv[i + SEL_T], kc = kv[i + 2 * SEL_T], kd = kv[i + 3 * SEL_T];
            CACC(ka, 4 * i); CACC(kb, 4 * (i + SEL_T)); CACC(kc, 4 * (i + 2 * SEL_T)); CACC(kd, 4 * (i + 3 * SEL_T));
        }
        for (; i < hiEnd; i += SEL_T) { uint4 ka = kv[i]; CACC(ka, 4 * i); }
    }
    __syncthreads();
    const int n = min(lcnt, SL_CAP);   // n >= 512 guaranteed by pivot
    for (int q = tid; q < SL_CAP; q += SEL_T) if (q >= n) lbuf[q] = ~0ULL;
    __syncthreads();

    // --- bitonic 1024 sort: 8 waves x (2 regs x 64 lanes) ---
    {
        const int l = tid & 63, w = tid >> 6;
        const int i0 = 128 * w + l, i1 = i0 + 64;
        u64 v0 = lbuf[i0], v1 = lbuf[i1];
        __syncthreads();
        #pragma unroll
        for (u32 kk = 2; kk <= 1024; kk <<= 1) {
            #pragma unroll
            for (u32 j = kk >> 1; j > 0; j >>= 1) {
                if (j >= 128) {
                    lbuf[i0] = v0; lbuf[i1] = v1;
                    __syncthreads();
                    u64 w0 = lbuf[i0 ^ j], w1 = lbuf[i1 ^ j];
                    bool m0 = (((i0 & j) == 0) == ((i0 & kk) == 0));
                    bool m1 = (((i1 & j) == 0) == ((i1 & kk) == 0));
                    v0 = m0 ? (v0 < w0 ? v0 : w0) : (v0 > w0 ? v0 : w0);
                    v1 = m1 ? (v1 < w1 ? v1 : w1) : (v1 > w1 ? v1 : w1);
                    __syncthreads();
                } else if (j == 64) {
                    bool up = ((i0 & kk) == 0);
                    u64 mn = v0 < v1 ? v0 : v1, mx = v0 < v1 ? v1 : v0;
                    v0 = up ? mn : mx; v1 = up ? mx : mn;
                } else {
                    u64 w0 = shflx64(v0, (int)j), w1 = shflx64(v1, (int)j);
                    bool m0 = (((i0 & j) == 0) == ((i0 & kk) == 0));
                    bool m1 = (((i1 & j) == 0) == ((i1 & kk) == 0));
                    v0 = m0 ? (v0 < w0 ? v0 : w0) : (v0 > w0 ? v0 : w0);
                    v1 = m1 ? (v1 < w1 ? v1 : w1) : (v1 > w1 ? v1 : w1);
                }
            }
        }
        if (w < 4) {   // i0, i1 in [0, 512)
            u64* cb = candbuf + (size_t)c * CAND_N + (size_t)s * KCAND;
            const bool rev = (s & 1);
            int d0 = rev ? (KCAND - 1 - i0) : i0;
            int d1 = rev ? (KCAND - 1 - i1) : i1;
            cb[d0] = v0; cb[d1] = v1;
        }
    }
}

// ---- Stage 3: fused resume-bitonic(2048) + ballot IoU mask + scan + compact ----
__global__ __launch_bounds__(1024)
void nms_kernel(const u64* __restrict__ candbuf,
                const float4* __restrict__ boxes,
                u32* __restrict__ keptbuf, u32* __restrict__ cnt2) {
    __shared__ u64 sortbuf[2][CAND_N];     // 32 KB; reused as bmask after sort
    __shared__ float bxx[KCAND], byy[KCAND], bzz[KCAND], bww[KCAND];
    __shared__ float ar[KCAND], sc[KCAND];
    __shared__ u32 keepf[16], wbase[17];
    u32* bmask = (u32*)&sortbuf[0][0];     // 512 rows x 16 words = 32 KB
    const int c = blockIdx.x, tid = threadIdx.x;
    const int l = tid & 63, w = tid >> 6;
    const int i0 = 128 * w + l, i1 = i0 + 64;

    // input: 4 sorted runs of 512, alternating asc/desc = post-stage-512 state
    const u64* cb = candbuf + (size_t)c * CAND_N;
    u64 v0 = cb[i0], v1 = cb[i1];
    int p = 0;
    #pragma unroll
    for (u32 kk = 1024; kk <= (u32)CAND_N; kk <<= 1) {
        #pragma unroll
        for (u32 j = kk >> 1; j > 0; j >>= 1) {
            if (j >= 128) {
                sortbuf[p][i0] = v0; sortbuf[p][i1] = v1;
                __syncthreads();
                u64 w0 = sortbuf[p][i0 ^ j], w1 = sortbuf[p][i1 ^ j];
                bool m0 = (((i0 & j) == 0) == ((i0 & kk) == 0));
                bool m1 = (((i1 & j) == 0) == ((i1 & kk) == 0));
                v0 = m0 ? (v0 < w0 ? v0 : w0) : (v0 > w0 ? v0 : w0);
                v1 = m1 ? (v1 < w1 ? v1 : w1) : (v1 > w1 ? v1 : w1);
                p ^= 1;
            } else if (j == 64) {
                bool up = ((i0 & kk) == 0);
                u64 mn = v0 < v1 ? v0 : v1, mx = v0 < v1 ? v1 : v0;
                v0 = up ? mn : mx; v1 = up ? mx : mn;
            } else {
                u64 w0 = shflx64(v0, (int)j), w1 = shflx64(v1, (int)j);
                bool m0 = (((i0 & j) == 0) == ((i0 & kk) == 0));
                bool m1 = (((i1 & j) == 0) == ((i1 & kk) == 0));
                v0 = m0 ? (v0 < w0 ? v0 : w0) : (v0 > w0 ? v0 : w0);
                v1 = m1 ? (v1 < w1 ? v1 : w1) : (v1 > w1 ? v1 : w1);
            }
        }
    }
    __syncthreads();   // sort done in registers; sortbuf free for bmask

    // --- top-512 -> SoA ---
    if (w < 4) {   // i0,i1 < 512
        u32 idx0 = (u32)v0, key0 = ~((u32)(v0 >> 32));
        u32 idx1 = (u32)v1, key1 = ~((u32)(v1 >> 32));
        sc[i0] = unfkey(key0); sc[i1] = unfkey(key1);
        float4 b0 = boxes[idx0], b1 = boxes[idx1];
        bxx[i0] = b0.x; byy[i0] = b0.y; bzz[i0] = b0.z; bww[i0] = b0.w;
        bxx[i1] = b1.x; byy[i1] = b1.y; bzz[i1] = b1.z; bww[i1] = b1.w;
        ar[i0] = (b0.z - b0.x) * (b0.w - b0.y);
        ar[i1] = (b1.z - b1.x) * (b1.w - b1.y);
    }
    if (tid < 16) keepf[tid] = 0;
    __syncthreads();

    // --- IoU mask: wave-per-row; column boxes register-resident ---
    {
        // preload lane's 8 column boxes (j = q*64 + l, invariant across rows)
        float jx[8], jy[8], jz[8], jw8[8], ja[8];
        #pragma unroll
        for (int q = 0; q < 8; ++q) {
            const int j = q * 64 + l;
            jx[q] = bxx[j]; jy[q] = byy[j]; jz[q] = bzz[j]; jw8[q] = bww[j];
            ja[q] = ar[j];
        }
        for (int r = w; r < KCAND; r += 16) {
            const float bix = bxx[r], biy = byy[r], biz = bzz[r], biw = bww[r];
            const float ai = ar[r];
            const int q0 = (r + 1) >> 6;              // wave-uniform
            u32* row = bmask + r * 16;
            if (l < 2 * q0) row[l] = 0;               // words below diagonal
            #pragma unroll
            for (int q = 0; q < 8; ++q) {
                if (q >= q0) {                        // wave-uniform branch
                    const int j = q * 64 + l;
                    float xx1 = fmaxf(bix, jx[q]), yy1 = fmaxf(biy, jy[q]);
                    float xx2 = fminf(biz, jz[q]), yy2 = fminf(biw, jw8[q]);
                    float inter = fmaxf(xx2 - xx1, 0.0f) * fmaxf(yy2 - yy1, 0.0f);
                    float uni = ai + ja[q] - inter + 1e-8f;   // identical expr order
                    bool sup = (j > r) && (inter > 0.5f * uni);
                    u64 bal = __ballot(sup);
                    if (l == 0)      row[2 * q]     = (u32)bal;
                    else if (l == 1) row[2 * q + 1] = (u32)(bal >> 32);
                }
            }
        }
    }
    __syncthreads();

    // --- greedy scan, wave 0; register-pipelined rows + readlane chain ---
    if (tid < 64) {
        const int lw = tid & 15;
        u32 removed = 0, keepw = 0;
        u32 rA[8], rB[8]; float sA[8], sB[8];
        #pragma unroll
        for (int k = 0; k < 8; ++k) { rA[k] = bmask[k * 16 + lw]; sA[k] = sc[k]; }
        #pragma unroll 1
        for (int ch = 0; ch < 64; ch += 2) {
            const int tb1 = (ch + 1) * 8;
            #pragma unroll
            for (int k = 0; k < 8; ++k) { rB[k] = bmask[(tb1 + k) * 16 + lw]; sB[k] = sc[tb1 + k]; }
            {
                const int tb = ch * 8;
                #pragma unroll
                for (int k = 0; k < 8; ++k) {
                    const int t = tb + k;
                    u32 rw = (u32)__builtin_amdgcn_readlane((int)removed, t >> 5);
                    bool d = (sA[k] > THRESH) && (((rw >> (t & 31)) & 1u) == 0u);
                    removed |= d ? rA[k] : 0u;
                    keepw |= (d && (tid == (t >> 5))) ? (1u << (t & 31)) : 0u;
                }
            }
            const int tb2 = (ch + 2 < 64) ? (ch + 2) * 8 : 0;
            #pragma unroll
            for (int k = 0; k < 8; ++k) { rA[k] = bmask[(tb2 + k) * 16 + lw]; sA[k] = sc[tb2 + k]; }
            {
                #pragma unroll
                for (int k = 0; k < 8; ++k) {
                    const int t = tb1 + k;
                    u32 rw = (u32)__builtin_amdgcn_readlane((int)removed, t >> 5);
                    bool d = (sB[k] > THRESH) && (((rw >> (t & 31)) & 1u) == 0u);
                    removed |= d ? rB[k] : 0u;
                    keepw |= (d && (tid == (t >> 5))) ? (1u << (t & 31)) : 0u;
                }
            }
        }
        if (tid < 16) keepf[tid] = keepw;
    }
    __syncthreads();

    // --- compact kept (sorted order) to keptbuf, cap 100/class ---
    if (tid == 0) {
        u32 t = 0;
        for (int q = 0; q < 16; ++q) { wbase[q] = t; t += __popc(keepf[q]); }
        wbase[16] = t;
        cnt2[c] = (t < (u32)KEEP_CAP) ? t : (u32)KEEP_CAP;
    }
    __syncthreads();
    if (tid < KCAND) {
        u32 word = keepf[tid >> 5];
        u32 bit = (u32)tid & 31u;
        if ((word >> bit) & 1u) {
            u32 rank = wbase[tid >> 5] + __popc(word & ((1u << bit) - 1u));
            if (rank < (u32)KEEP_CAP) {
                float s = sc[tid];
                uint4 a, b;
                a.x = ~fkey(s);
                a.y = (u32)(c * KCAND + tid);
                a.z = __float_as_uint(bxx[tid]);
                a.w = __float_as_uint(byy[tid]);
                b.x = __float_as_uint(bzz[tid]);
                b.y = __float_as_uint(bww[tid]);
                b.z = __float_as_uint(s);
                b.w = 0u;
                uint4* e = (uint4*)(keptbuf + ((size_t)c * KEEP_CAP + rank) * 8);
                e[0] = a; e[1] = b;
            }
        }
    }
}

// ---- Stage 4: global top-100 via hist-select over <=9000 kept entries ----
__global__ __launch_bounds__(1024)
void final_kernel(const u32* __restrict__ keptbuf, const u32* __restrict__ cnt2,
                  float* __restrict__ out) {
    __shared__ u32 hist[NBINS];    // 32 KB
    __shared__ u32 csum[1024];     // 4 KB
    __shared__ u64 ebuf[FCAP];     // 4 KB keys
    __shared__ u32 eidx[FCAP];     // 2 KB payload (keptbuf entry index)
    __shared__ u32 scnt[C_N];
    __shared__ u32 sP;
    __shared__ int sN;
    const int tid = threadIdx.x;
    const int TOT = C_N * KEEP_CAP;   // 9000

    for (int i = tid; i < MAXDET * 7; i += 1024) out[i] = 0.0f;
    for (int i = tid; i < NBINS; i += 1024) hist[i] = 0;
    if (tid < C_N) scnt[tid] = cnt2[tid];
    if (tid == 0) { sN = 0; sP = NBINS - 1; }
    __syncthreads();

    // hist over composite high word (smaller = better -> ascending pivot)
    for (int i = tid; i < TOT; i += 1024) {
        u32 c = (u32)i / KEEP_CAP, pp = (u32)i % KEEP_CAP;
        if (pp < scnt[c]) {
            u32 khi = keptbuf[(size_t)i * 8];   // a.x = ~fkey(s)
            atomicAdd(&hist[khi >> KSH], 1u);
        }
    }
    __syncthreads();
    // ascending chunk sums (8 bins each) + Hillis-Steele scan
    u32 own = 0; const int lo = 8 * tid;
    #pragma unroll
    for (int j = 0; j < 8; ++j) own += hist[lo + j];
    csum[tid] = own;
    __syncthreads();
    for (int off = 1; off < 1024; off <<= 1) {
        u32 v = csum[tid];
        u32 a = (tid >= off) ? csum[tid - off] : 0u;
        __syncthreads();
        csum[tid] = v + a;
        __syncthreads();
    }
    const u32 incl = csum[tid], excl = incl - own;
    if (excl < (u32)MAXDET && incl >= (u32)MAXDET) {
        u32 cum = excl;
        for (int j = 0; j < 8; ++j) {
            u32 h = hist[lo + j];
            if (cum + h >= (u32)MAXDET) { sP = (u32)(lo + j); break; }
            cum += h;
        }
    }
    __syncthreads();
    const u32 P = sP;
    // collect entries with bin <= P
    for (int i = tid; i < TOT; i += 1024) {
        u32 c = (u32)i / KEEP_CAP, pp = (u32)i % KEEP_CAP;
        if (pp < scnt[c]) {
            const uint2 v2 = *((const uint2*)(keptbuf + (size_t)i * 8));
            if ((v2.x >> KSH) <= P) {
                int p = atomicAdd(&sN, 1);
                if (p < FCAP) {
                    ebuf[p] = ((u64)v2.x << 32) | v2.y;
                    eidx[p] = (u32)i;
                }
            }
        }
    }
    __syncthreads();
    const int n = min(sN, FCAP);
    u32 m = 128; while ((int)m < n) m <<= 1;   // 128..512, uniform
    for (int i = tid; i < (int)m; i += 1024) if (i >= n) ebuf[i] = ~0ULL;
    __syncthreads();
    // bitonic sort (key ebuf asc, payload eidx follows)
    for (u32 kk = 2; kk <= m; kk <<= 1) {
        for (u32 j = kk >> 1; j > 0; j >>= 1) {
            u32 i = (u32)tid;
            if (i < m) {
                u32 ixj = i ^ j;
                if (ixj > i) {
                    u64 x = ebuf[i], y = ebuf[ixj];
                    bool up = ((i & kk) == 0);
                    if (up ? (x > y) : (x < y)) {
                        ebuf[i] = y; ebuf[ixj] = x;
                        u32 t = eidx[i]; eidx[i] = eidx[ixj]; eidx[ixj] = t;
                    }
                }
            }
            __syncthreads();
        }
    }
    if (tid < MAXDET && tid < n) {
        u64 comp = ebuf[tid];
        if (comp != ~0ULL) {
            const uint4* e = (const uint4*)(keptbuf + (size_t)eidx[tid] * 8);
            uint4 a = e[0], b = e[1];
            float* o = out + tid * 7;
            o[0] = 0.0f;
            o[1] = __uint_as_float(a.z); o[2] = __uint_as_float(a.w);
            o[3] = __uint_as_float(b.x); o[4] = __uint_as_float(b.y);
            o[5] = __uint_as_float(b.z);
            o[6] = (float)(((u32)comp) >> 9);   // low word = c*512+pos -> class
        }
    }
}

extern "C" void kernel_launch(void* const* d_in, const int* in_sizes, int n_in,
                              void* d_out, int out_size, void* d_ws, size_t ws_size,
                              hipStream_t stream) {
    const float* reg     = (const float*)d_in[1];
    const float* cls     = (const float*)d_in[2];
    const float* anchors = (const float*)d_in[3];
    float* out = (float*)d_out;

    char* ws = (char*)d_ws;
    size_t off = 0;
    auto alloc = [&](size_t bytes) -> void* {
        void* p = ws + off;
        off = (off + bytes + 255) & ~(size_t)255;
        return p;
    };
    u32*    keysT   = (u32*)   alloc((size_t)C_N * A_N * sizeof(u32));          // 39.8 MB
    float4* boxes   = (float4*)alloc((size_t)A_N * sizeof(float4));             // 1.77 MB
    u64*    candbuf = (u64*)   alloc((size_t)C_N * CAND_N * sizeof(u64));       // 1.47 MB
    u32*    keptbuf = (u32*)   alloc((size_t)C_N * KEEP_CAP * 8 * sizeof(u32)); // 288 KB
    u32*    cnt2    = (u32*)   alloc((size_t)C_N * sizeof(u32));
    (void)ws_size;

    prep_kernel<<<T_BLKS, 256, 0, stream>>>(cls, keysT);
    select_kernel<<<S_BLKS + D_BLKS, SEL_T, 0, stream>>>(keysT, anchors, reg, boxes, candbuf);
    nms_kernel<<<C_N, 1024, 0, stream>>>(candbuf, boxes, keptbuf, cnt2);
    final_kernel<<<1, 1024, 0, stream>>>(keptbuf, cnt2, out);
}

// Round 4
// 184.239 us; speedup vs baseline: 1.2265x; 1.1207x over previous
//
#include <hip/hip_runtime.h>
#include <math.h>

// EfficientDet post-processing v15 (4 launches).
// prep(transpose vec4) -> select(512-thr, u16-hist sorted top-512 per (class,slice) + decode)
// -> nms(resume-bitonic + named-scalar-register ballot IoU mask + early-exit greedy scan)
// -> final(hist-select top-100 over <=9000 kept entries).
// v15: mask column boxes in NAMED float4 scalars (v14's arrays never became
// registers: VGPR stayed 32), b64 ballot writes, scan early-exit at 100 kept.

#define A_N   110484
#define C_N   90
#define KCAND 512
#define NBINS 8192        // 13-bit histogram bins (key >> 19)
#define KSH   19
#define MAXDET 100
#define IMG_F 768.0f
#define THRESH 0.05f
#define NS    4                                   // slices per class
#define VTOT  (A_N / 4)                           // 27621 vec4 units
#define VS4   ((VTOT + NS - 1) / NS)              // 6906
#define SL_CAP 1024                               // per-slice candidate cap
#define CAND_N (NS * KCAND)                       // 2048 per class (sorted runs)
#define KEEP_CAP 100
#define T_BLKS ((A_N + 63) / 64)                  // 1727 transpose blocks
#define S_BLKS (C_N * NS)                         // 360 select blocks
#define SEL_T 512
#define D_BLKS ((A_N + SEL_T - 1) / SEL_T)        // 216 decode blocks
#define FCAP  512                                 // final collect capacity

typedef unsigned int u32;
typedef unsigned long long u64;

__device__ __forceinline__ u32 fkey(float f) {
    u32 u = __float_as_uint(f);
    return (u & 0x80000000u) ? ~u : (u | 0x80000000u);
}
__device__ __forceinline__ float unfkey(u32 k) {
    u32 u = (k & 0x80000000u) ? (k ^ 0x80000000u) : ~k;
    return __uint_as_float(u);
}
__device__ __forceinline__ u64 shflx64(u64 v, int m) {
    u32 lo = (u32)__shfl_xor((int)(u32)v, m, 64);
    u32 hi = (u32)__shfl_xor((int)(v >> 32), m, 64);
    return ((u64)hi << 32) | lo;
}

// ------- Stage 1: transpose (sigmoid->key, vec4 loads) -------
__global__ __launch_bounds__(256)
void prep_kernel(const float* __restrict__ cls,
                 u32* __restrict__ keysT) {
    __shared__ u32 tile[64 * 91];   // 23.3 KB, stride 91 (odd) = conflict-free
    const int a0 = blockIdx.x * 64;
    const int lim = min(64, A_N - a0);           // 64 or 20; lim*90 % 4 == 0
    const int n4 = (lim * C_N) >> 2;
    const float4* src4 = (const float4*)(cls + (size_t)a0 * C_N);
    for (int i4 = threadIdx.x; i4 < n4; i4 += 256) {
        float4 x4 = src4[i4];
        const u32 base = (u32)(4 * i4);
        float xs[4] = { x4.x, x4.y, x4.z, x4.w };
        #pragma unroll
        for (int k = 0; k < 4; ++k) {
            u32 i = base + k;
            u32 aa = i / C_N, c = i % C_N;
            float s = 1.0f / (1.0f + expf(-xs[k]));
            tile[aa * 91 + c] = fkey(s);
        }
    }
    __syncthreads();
    for (int j = threadIdx.x; j < C_N * 64; j += 256) {
        int c = j >> 6, aa = j & 63;
        if (aa < lim)
            keysT[(size_t)c * A_N + a0 + aa] = tile[aa * 91 + c];
    }
}

// ---- Stage 2: per-(class,slice) exact sorted top-512 (+ decode blocks) ----
// 512 threads, u16-packed hist (16 KB), 4-wide unrolled global loads.
__global__ __launch_bounds__(SEL_T)
void select_kernel(const u32* __restrict__ keysT,
                   const float* __restrict__ anchors,
                   const float* __restrict__ reg,
                   float4* __restrict__ boxes,
                   u64* __restrict__ candbuf) {
    __shared__ u32 hist[NBINS / 2];   // 16 KB, two u16 counters per word
    __shared__ u32 csum[SEL_T];       // 2 KB
    __shared__ u64 lbuf[SL_CAP];      // 8 KB
    __shared__ u32 sPv;
    __shared__ int lcnt;
    const int tid = threadIdx.x;

    if (blockIdx.x >= S_BLKS) {    // decode blocks
        int a = (blockIdx.x - S_BLKS) * SEL_T + tid;
        if (a < A_N) {
            float4 an = ((const float4*)anchors)[a];
            float4 dl = ((const float4*)reg)[a];
            float wa = an.z - an.x, ha = an.w - an.y;
            float cx = an.x + 0.5f * wa + dl.x * wa;
            float cy = an.y + 0.5f * ha + dl.y * ha;
            float w = expf(dl.z) * wa;
            float h = expf(dl.w) * ha;
            float4 o;
            o.x = fminf(fmaxf(cx - 0.5f * w, 0.0f), IMG_F);
            o.y = fminf(fmaxf(cy - 0.5f * h, 0.0f), IMG_F);
            o.z = fminf(fmaxf(cx + 0.5f * w, 0.0f), IMG_F);
            o.w = fminf(fmaxf(cy + 0.5f * h, 0.0f), IMG_F);
            boxes[a] = o;
        }
        return;
    }
    const int c = blockIdx.x >> 2, s = blockIdx.x & 3;
    const int lo = s * VS4, hiEnd = min(VTOT, lo + VS4);
    const uint4* kv = (const uint4*)(keysT + (size_t)c * A_N);

    for (int i = tid; i < NBINS / 2; i += SEL_T) hist[i] = 0;
    if (tid == 0) { sPv = 0; lcnt = 0; }
    __syncthreads();

    // --- pass 1: histogram (counts packed: even bin = low half, odd = high) ---
    #define HACC(K) do { \
        u32 b0 = (K).x >> KSH, b1 = (K).y >> KSH, b2 = (K).z >> KSH, b3 = (K).w >> KSH; \
        atomicAdd(&hist[b0 >> 1], 1u << ((b0 & 1) << 4)); \
        atomicAdd(&hist[b1 >> 1], 1u << ((b1 & 1) << 4)); \
        atomicAdd(&hist[b2 >> 1], 1u << ((b2 & 1) << 4)); \
        atomicAdd(&hist[b3 >> 1], 1u << ((b3 & 1) << 4)); } while (0)
    {
        int i = lo + tid;
        for (; i + 3 * SEL_T < hiEnd; i += 4 * SEL_T) {
            uint4 ka = kv[i], kb = kv[i + SEL_T], kc = kv[i + 2 * SEL_T], kd = kv[i + 3 * SEL_T];
            HACC(ka); HACC(kb); HACC(kc); HACC(kd);
        }
        for (; i < hiEnd; i += SEL_T) { uint4 ka = kv[i]; HACC(ka); }
    }
    __syncthreads();

    // --- chunk sums (16 bins = 8 words per thread, descending), rotated reads ---
    u32 own = 0;
    {
        const int wb = (NBINS / 2) - 8 - 8 * tid;   // lowest word of my chunk
        const int g = (tid >> 2) & 7;               // rotation -> 2 lanes/bank
        #pragma unroll
        for (int jj = 0; jj < 8; ++jj) {
            u32 v = hist[wb + ((g + jj) & 7)];
            own += (v & 0xffffu) + (v >> 16);
        }
    }
    csum[tid] = own;
    __syncthreads();
    for (int off = 1; off < SEL_T; off <<= 1) {
        u32 v = csum[tid];
        u32 a = (tid >= off) ? csum[tid - off] : 0u;
        __syncthreads();
        csum[tid] = v + a;
        __syncthreads();
    }
    const u32 incl = csum[tid], excl = incl - own;
    if (excl < (u32)KCAND && incl >= (u32)KCAND) {
        u32 cum = excl;
        const int hb = NBINS - 1 - 16 * tid;
        for (int j = 0; j < 16; ++j) {
            int b = hb - j;
            u32 v = hist[b >> 1];
            u32 cnt = (b & 1) ? (v >> 16) : (v & 0xffffu);
            if (cum + cnt >= (u32)KCAND) { sPv = (u32)b; break; }
            cum += cnt;
        }
    }
    __syncthreads();
    const u32 P = sPv;

    // --- pass 2: collect candidates >= pivot bin ---
    #define CACC(K, BASE) do { \
        if (((K).x >> KSH) >= P) { int p = atomicAdd(&lcnt, 1); if (p < SL_CAP) lbuf[p] = (((u64)(~(K).x)) << 32) | (u32)(BASE); } \
        if (((K).y >> KSH) >= P) { int p = atomicAdd(&lcnt, 1); if (p < SL_CAP) lbuf[p] = (((u64)(~(K).y)) << 32) | (u32)((BASE) + 1); } \
        if (((K).z >> KSH) >= P) { int p = atomicAdd(&lcnt, 1); if (p < SL_CAP) lbuf[p] = (((u64)(~(K).z)) << 32) | (u32)((BASE) + 2); } \
        if (((K).w >> KSH) >= P) { int p = atomicAdd(&lcnt, 1); if (p < SL_CAP) lbuf[p] = (((u64)(~(K).w)) << 32) | (u32)((BASE) + 3); } } while (0)
    {
        int i = lo + tid;
        for (; i + 3 * SEL_T < hiEnd; i += 4 * SEL_T) {
            uint4 ka = kv[i], kb = kv[i + SEL_T], kc = kv[i + 2 * SEL_T], kd = kv[i + 3 * SEL_T];
            CACC(ka, 4 * i); CACC(kb, 4 * (i + SEL_T)); CACC(kc, 4 * (i + 2 * SEL_T)); CACC(kd, 4 * (i + 3 * SEL_T));
        }
        for (; i < hiEnd; i += SEL_T) { uint4 ka = kv[i]; CACC(ka, 4 * i); }
    }
    __syncthreads();
    const int n = min(lcnt, SL_CAP);   // n >= 512 guaranteed by pivot
    for (int q = tid; q < SL_CAP; q += SEL_T) if (q >= n) lbuf[q] = ~0ULL;
    __syncthreads();

    // --- bitonic 1024 sort: 8 waves x (2 regs x 64 lanes) ---
    {
        const int l = tid & 63, w = tid >> 6;
        const int i0 = 128 * w + l, i1 = i0 + 64;
        u64 v0 = lbuf[i0], v1 = lbuf[i1];
        __syncthreads();
        #pragma unroll
        for (u32 kk = 2; kk <= 1024; kk <<= 1) {
            #pragma unroll
            for (u32 j = kk >> 1; j > 0; j >>= 1) {
                if (j >= 128) {
                    lbuf[i0] = v0; lbuf[i1] = v1;
                    __syncthreads();
                    u64 w0 = lbuf[i0 ^ j], w1 = lbuf[i1 ^ j];
                    bool m0 = (((i0 & j) == 0) == ((i0 & kk) == 0));
                    bool m1 = (((i1 & j) == 0) == ((i1 & kk) == 0));
                    v0 = m0 ? (v0 < w0 ? v0 : w0) : (v0 > w0 ? v0 : w0);
                    v1 = m1 ? (v1 < w1 ? v1 : w1) : (v1 > w1 ? v1 : w1);
                    __syncthreads();
                } else if (j == 64) {
                    bool up = ((i0 & kk) == 0);
                    u64 mn = v0 < v1 ? v0 : v1, mx = v0 < v1 ? v1 : v0;
                    v0 = up ? mn : mx; v1 = up ? mx : mn;
                } else {
                    u64 w0 = shflx64(v0, (int)j), w1 = shflx64(v1, (int)j);
                    bool m0 = (((i0 & j) == 0) == ((i0 & kk) == 0));
                    bool m1 = (((i1 & j) == 0) == ((i1 & kk) == 0));
                    v0 = m0 ? (v0 < w0 ? v0 : w0) : (v0 > w0 ? v0 : w0);
                    v1 = m1 ? (v1 < w1 ? v1 : w1) : (v1 > w1 ? v1 : w1);
                }
            }
        }
        if (w < 4) {   // i0, i1 in [0, 512)
            u64* cb = candbuf + (size_t)c * CAND_N + (size_t)s * KCAND;
            const bool rev = (s & 1);
            int d0 = rev ? (KCAND - 1 - i0) : i0;
            int d1 = rev ? (KCAND - 1 - i1) : i1;
            cb[d0] = v0; cb[d1] = v1;
        }
    }
}

// ---- Stage 3: fused resume-bitonic(2048) + ballot IoU mask + scan + compact ----
__global__ __launch_bounds__(1024, 4)
void nms_kernel(const u64* __restrict__ candbuf,
                const float4* __restrict__ boxes,
                u32* __restrict__ keptbuf, u32* __restrict__ cnt2) {
    __shared__ u64 sortbuf[2][CAND_N];     // 32 KB; reused as bmask after sort
    __shared__ float4 bb4[KCAND];          // 8 KB
    __shared__ float sc[KCAND];            // 2 KB
    __shared__ u32 keepf[16], wbase[17];
    u32* bmask = (u32*)&sortbuf[0][0];     // 512 rows x 16 words = 32 KB
    const int c = blockIdx.x, tid = threadIdx.x;
    const int l = tid & 63, w = tid >> 6;
    const int i0 = 128 * w + l, i1 = i0 + 64;

    // input: 4 sorted runs of 512, alternating asc/desc = post-stage-512 state
    const u64* cb = candbuf + (size_t)c * CAND_N;
    u64 v0 = cb[i0], v1 = cb[i1];
    int p = 0;
    #pragma unroll
    for (u32 kk = 1024; kk <= (u32)CAND_N; kk <<= 1) {
        #pragma unroll
        for (u32 j = kk >> 1; j > 0; j >>= 1) {
            if (j >= 128) {
                sortbuf[p][i0] = v0; sortbuf[p][i1] = v1;
                __syncthreads();
                u64 w0 = sortbuf[p][i0 ^ j], w1 = sortbuf[p][i1 ^ j];
                bool m0 = (((i0 & j) == 0) == ((i0 & kk) == 0));
                bool m1 = (((i1 & j) == 0) == ((i1 & kk) == 0));
                v0 = m0 ? (v0 < w0 ? v0 : w0) : (v0 > w0 ? v0 : w0);
                v1 = m1 ? (v1 < w1 ? v1 : w1) : (v1 > w1 ? v1 : w1);
                p ^= 1;
            } else if (j == 64) {
                bool up = ((i0 & kk) == 0);
                u64 mn = v0 < v1 ? v0 : v1, mx = v0 < v1 ? v1 : v0;
                v0 = up ? mn : mx; v1 = up ? mx : mn;
            } else {
                u64 w0 = shflx64(v0, (int)j), w1 = shflx64(v1, (int)j);
                bool m0 = (((i0 & j) == 0) == ((i0 & kk) == 0));
                bool m1 = (((i1 & j) == 0) == ((i1 & kk) == 0));
                v0 = m0 ? (v0 < w0 ? v0 : w0) : (v0 > w0 ? v0 : w0);
                v1 = m1 ? (v1 < w1 ? v1 : w1) : (v1 > w1 ? v1 : w1);
            }
        }
    }
    __syncthreads();   // sort done in registers; sortbuf free for bmask

    // --- top-512 -> SoA (areas recomputed on demand: 3 VALU < 1 LDS read) ---
    if (w < 4) {   // i0,i1 < 512
        u32 idx0 = (u32)v0, key0 = ~((u32)(v0 >> 32));
        u32 idx1 = (u32)v1, key1 = ~((u32)(v1 >> 32));
        sc[i0] = unfkey(key0); sc[i1] = unfkey(key1);
        bb4[i0] = boxes[idx0]; bb4[i1] = boxes[idx1];
    }
    if (tid < 16) keepf[tid] = 0;
    __syncthreads();

    // --- IoU mask: wave-per-row; column boxes in NAMED register scalars ---
    {
        // lane's 8 column boxes (j = q*64 + l, invariant across this wave's rows)
        const float4 cj0 = bb4[0 * 64 + l], cj1 = bb4[1 * 64 + l];
        const float4 cj2 = bb4[2 * 64 + l], cj3 = bb4[3 * 64 + l];
        const float4 cj4 = bb4[4 * 64 + l], cj5 = bb4[5 * 64 + l];
        const float4 cj6 = bb4[6 * 64 + l], cj7 = bb4[7 * 64 + l];
        const float aj0 = (cj0.z - cj0.x) * (cj0.w - cj0.y);
        const float aj1 = (cj1.z - cj1.x) * (cj1.w - cj1.y);
        const float aj2 = (cj2.z - cj2.x) * (cj2.w - cj2.y);
        const float aj3 = (cj3.z - cj3.x) * (cj3.w - cj3.y);
        const float aj4 = (cj4.z - cj4.x) * (cj4.w - cj4.y);
        const float aj5 = (cj5.z - cj5.x) * (cj5.w - cj5.y);
        const float aj6 = (cj6.z - cj6.x) * (cj6.w - cj6.y);
        const float aj7 = (cj7.z - cj7.x) * (cj7.w - cj7.y);

        #define QSTEP(QQ, CJ, AJ) do { \
            if (QQ >= q0) { \
                float xx1 = fmaxf(bi.x, (CJ).x), yy1 = fmaxf(bi.y, (CJ).y); \
                float xx2 = fminf(bi.z, (CJ).z), yy2 = fminf(bi.w, (CJ).w); \
                float inter = fmaxf(xx2 - xx1, 0.0f) * fmaxf(yy2 - yy1, 0.0f); \
                float uni = ai + (AJ) - inter + 1e-8f; \
                bool sup = ((QQ * 64 + l) > r) && (inter > 0.5f * uni); \
                u64 bal = __ballot(sup); \
                if (l == 0) *(u64*)(row + 2 * QQ) = bal; \
            } } while (0)

        for (int r = w; r < KCAND; r += 16) {
            const float4 bi = bb4[r];                 // broadcast read
            const float ai = (bi.z - bi.x) * (bi.w - bi.y);
            const int q0 = (r + 1) >> 6;              // wave-uniform
            u32* row = bmask + r * 16;
            if (l < 2 * q0) row[l] = 0;               // words below diagonal
            QSTEP(0, cj0, aj0); QSTEP(1, cj1, aj1);
            QSTEP(2, cj2, aj2); QSTEP(3, cj3, aj3);
            QSTEP(4, cj4, aj4); QSTEP(5, cj5, aj5);
            QSTEP(6, cj6, aj6); QSTEP(7, cj7, aj7);
        }
        #undef QSTEP
    }
    __syncthreads();

    // --- greedy scan, wave 0; register-pipelined rows + readlane chain ---
    // Early exit: kept entries are produced in sorted order and capped at
    // KEEP_CAP; once >=100 kept, later rows cannot affect output.
    if (tid < 64) {
        const int lw = tid & 15;
        u32 removed = 0, keepw = 0;
        u32 rA[8], rB[8]; float sA[8], sB[8];
        #pragma unroll
        for (int k = 0; k < 8; ++k) { rA[k] = bmask[k * 16 + lw]; sA[k] = sc[k]; }
        #pragma unroll 1
        for (int ch = 0; ch < 64; ch += 2) {
            const int tb1 = (ch + 1) * 8;
            #pragma unroll
            for (int k = 0; k < 8; ++k) { rB[k] = bmask[(tb1 + k) * 16 + lw]; sB[k] = sc[tb1 + k]; }
            {
                const int tb = ch * 8;
                #pragma unroll
                for (int k = 0; k < 8; ++k) {
                    const int t = tb + k;
                    u32 rw = (u32)__builtin_amdgcn_readlane((int)removed, t >> 5);
                    bool d = (sA[k] > THRESH) && (((rw >> (t & 31)) & 1u) == 0u);
                    removed |= d ? rA[k] : 0u;
                    keepw |= (d && (tid == (t >> 5))) ? (1u << (t & 31)) : 0u;
                }
            }
            const int tb2 = (ch + 2 < 64) ? (ch + 2) * 8 : 0;
            #pragma unroll
            for (int k = 0; k < 8; ++k) { rA[k] = bmask[(tb2 + k) * 16 + lw]; sA[k] = sc[tb2 + k]; }
            {
                #pragma unroll
                for (int k = 0; k < 8; ++k) {
                    const int t = tb1 + k;
                    u32 rw = (u32)__builtin_amdgcn_readlane((int)removed, t >> 5);
                    bool d = (sB[k] > THRESH) && (((rw >> (t & 31)) & 1u) == 0u);
                    removed |= d ? rB[k] : 0u;
                    keepw |= (d && (tid == (t >> 5))) ? (1u << (t & 31)) : 0u;
                }
            }
            // early exit: total kept so far (keepw nonzero only on lanes 0-15)
            u32 cnt = (u32)__popc(keepw);
            #pragma unroll
            for (int m = 32; m; m >>= 1) cnt += (u32)__shfl_xor((int)cnt, m, 64);
            if (cnt >= (u32)KEEP_CAP) break;
        }
        if (tid < 16) keepf[tid] = keepw;
    }
    __syncthreads();

    // --- compact kept (sorted order) to keptbuf, cap 100/class ---
    if (tid == 0) {
        u32 t = 0;
        for (int q = 0; q < 16; ++q) { wbase[q] = t; t += __popc(keepf[q]); }
        wbase[16] = t;
        cnt2[c] = (t < (u32)KEEP_CAP) ? t : (u32)KEEP_CAP;
    }
    __syncthreads();
    if (tid < KCAND) {
        u32 word = keepf[tid >> 5];
        u32 bit = (u32)tid & 31u;
        if ((word >> bit) & 1u) {
            u32 rank = wbase[tid >> 5] + __popc(word & ((1u << bit) - 1u));
            if (rank < (u32)KEEP_CAP) {
                float s = sc[tid];
                float4 b = bb4[tid];
                uint4 a2, b2;
                a2.x = ~fkey(s);
                a2.y = (u32)(c * KCAND + tid);
                a2.z = __float_as_uint(b.x);
                a2.w = __float_as_uint(b.y);
                b2.x = __float_as_uint(b.z);
                b2.y = __float_as_uint(b.w);
                b2.z = __float_as_uint(s);
                b2.w = 0u;
                uint4* e = (uint4*)(keptbuf + ((size_t)c * KEEP_CAP + rank) * 8);
                e[0] = a2; e[1] = b2;
            }
        }
    }
}

// ---- Stage 4: global top-100 via hist-select over <=9000 kept entries ----
__global__ __launch_bounds__(1024)
void final_kernel(const u32* __restrict__ keptbuf, const u32* __restrict__ cnt2,
                  float* __restrict__ out) {
    __shared__ u32 hist[NBINS];    // 32 KB
    __shared__ u32 csum[1024];     // 4 KB
    __shared__ u64 ebuf[FCAP];     // 4 KB keys
    __shared__ u32 eidx[FCAP];     // 2 KB payload (keptbuf entry index)
    __shared__ u32 scnt[C_N];
    __shared__ u32 sP;
    __shared__ int sN;
    const int tid = threadIdx.x;
    const int TOT = C_N * KEEP_CAP;   // 9000

    for (int i = tid; i < MAXDET * 7; i += 1024) out[i] = 0.0f;
    for (int i = tid; i < NBINS; i += 1024) hist[i] = 0;
    if (tid < C_N) scnt[tid] = cnt2[tid];
    if (tid == 0) { sN = 0; sP = NBINS - 1; }
    __syncthreads();

    // hist over composite high word (smaller = better -> ascending pivot)
    for (int i = tid; i < TOT; i += 1024) {
        u32 c = (u32)i / KEEP_CAP, pp = (u32)i % KEEP_CAP;
        if (pp < scnt[c]) {
            u32 khi = keptbuf[(size_t)i * 8];   // a.x = ~fkey(s)
            atomicAdd(&hist[khi >> KSH], 1u);
        }
    }
    __syncthreads();
    // ascending chunk sums (8 bins each) + Hillis-Steele scan
    u32 own = 0; const int lo = 8 * tid;
    #pragma unroll
    for (int j = 0; j < 8; ++j) own += hist[lo + j];
    csum[tid] = own;
    __syncthreads();
    for (int off = 1; off < 1024; off <<= 1) {
        u32 v = csum[tid];
        u32 a = (tid >= off) ? csum[tid - off] : 0u;
        __syncthreads();
        csum[tid] = v + a;
        __syncthreads();
    }
    const u32 incl = csum[tid], excl = incl - own;
    if (excl < (u32)MAXDET && incl >= (u32)MAXDET) {
        u32 cum = excl;
        for (int j = 0; j < 8; ++j) {
            u32 h = hist[lo + j];
            if (cum + h >= (u32)MAXDET) { sP = (u32)(lo + j); break; }
            cum += h;
        }
    }
    __syncthreads();
    const u32 P = sP;
    // collect entries with bin <= P
    for (int i = tid; i < TOT; i += 1024) {
        u32 c = (u32)i / KEEP_CAP, pp = (u32)i % KEEP_CAP;
        if (pp < scnt[c]) {
            const uint2 v2 = *((const uint2*)(keptbuf + (size_t)i * 8));
            if ((v2.x >> KSH) <= P) {
                int p = atomicAdd(&sN, 1);
                if (p < FCAP) {
                    ebuf[p] = ((u64)v2.x << 32) | v2.y;
                    eidx[p] = (u32)i;
                }
            }
        }
    }
    __syncthreads();
    const int n = min(sN, FCAP);
    u32 m = 128; while ((int)m < n) m <<= 1;   // 128..512, uniform
    for (int i = tid; i < (int)m; i += 1024) if (i >= n) ebuf[i] = ~0ULL;
    __syncthreads();
    // bitonic sort (key ebuf asc, payload eidx follows)
    for (u32 kk = 2; kk <= m; kk <<= 1) {
        for (u32 j = kk >> 1; j > 0; j >>= 1) {
            u32 i = (u32)tid;
            if (i < m) {
                u32 ixj = i ^ j;
                if (ixj > i) {
                    u64 x = ebuf[i], y = ebuf[ixj];
                    bool up = ((i & kk) == 0);
                    if (up ? (x > y) : (x < y)) {
                        ebuf[i] = y; ebuf[ixj] = x;
                        u32 t = eidx[i]; eidx[i] = eidx[ixj]; eidx[ixj] = t;
                    }
                }
            }
            __syncthreads();
        }
    }
    if (tid < MAXDET && tid < n) {
        u64 comp = ebuf[tid];
        if (comp != ~0ULL) {
            const uint4* e = (const uint4*)(keptbuf + (size_t)eidx[tid] * 8);
            uint4 a = e[0], b = e[1];
            float* o = out + tid * 7;
            o[0] = 0.0f;
            o[1] = __uint_as_float(a.z); o[2] = __uint_as_float(a.w);
            o[3] = __uint_as_float(b.x); o[4] = __uint_as_float(b.y);
            o[5] = __uint_as_float(b.z);
            o[6] = (float)(((u32)comp) >> 9);   // low word = c*512+pos -> class
        }
    }
}

extern "C" void kernel_launch(void* const* d_in, const int* in_sizes, int n_in,
                              void* d_out, int out_size, void* d_ws, size_t ws_size,
                              hipStream_t stream) {
    const float* reg     = (const float*)d_in[1];
    const float* cls     = (const float*)d_in[2];
    const float* anchors = (const float*)d_in[3];
    float* out = (float*)d_out;

    char* ws = (char*)d_ws;
    size_t off = 0;
    auto alloc = [&](size_t bytes) -> void* {
        void* p = ws + off;
        off = (off + bytes + 255) & ~(size_t)255;
        return p;
    };
    u32*    keysT   = (u32*)   alloc((size_t)C_N * A_N * sizeof(u32));          // 39.8 MB
    float4* boxes   = (float4*)alloc((size_t)A_N * sizeof(float4));             // 1.77 MB
    u64*    candbuf = (u64*)   alloc((size_t)C_N * CAND_N * sizeof(u64));       // 1.47 MB
    u32*    keptbuf = (u32*)   alloc((size_t)C_N * KEEP_CAP * 8 * sizeof(u32)); // 288 KB
    u32*    cnt2    = (u32*)   alloc((size_t)C_N * sizeof(u32));
    (void)ws_size;

    prep_kernel<<<T_BLKS, 256, 0, stream>>>(cls, keysT);
    select_kernel<<<S_BLKS + D_BLKS, SEL_T, 0, stream>>>(keysT, anchors, reg, boxes, candbuf);
    nms_kernel<<<C_N, 1024, 0, stream>>>(candbuf, boxes, keptbuf, cnt2);
    final_kernel<<<1, 1024, 0, stream>>>(keptbuf, cnt2, out);
}